// Round 4
// baseline (1262.069 us; speedup 1.0000x reference)
//
#include <hip/hip_runtime.h>
#include <hip/hip_bf16.h>
#include <math.h>

typedef __bf16 bf16x8 __attribute__((ext_vector_type(8)));
typedef float f32x4 __attribute__((ext_vector_type(4)));
typedef unsigned short u16;
typedef unsigned int u32;

#define TOKENS 16384
#define MROWS  65536

__device__ __forceinline__ u16 f2bf(float f) {
  union { __hip_bfloat16 h; u16 u; } c;
  c.h = __float2bfloat16(f);
  return c.u;
}
__device__ __forceinline__ float bf2f(u16 u) {
  union { u16 u; __hip_bfloat16 h; } c;
  c.u = u;
  return __bfloat162float(c.h);
}

// ---------------- prep kernels ----------------
__global__ void kprep_G(const float* __restrict__ Wq, const float* __restrict__ Wk,
                        float* __restrict__ G) {
  int id = blockIdx.x * 256 + threadIdx.x;  // 16384
  int c = id >> 7, c2 = id & 127;
  const float4* a = (const float4*)(Wq + (size_t)c * 512);
  const float4* b = (const float4*)(Wk + (size_t)c2 * 512);
  float s = 0.f;
#pragma unroll 8
  for (int i = 0; i < 128; ++i) {
    float4 xa = a[i], yb = b[i];
    s += xa.x * yb.x + xa.y * yb.y + xa.z * yb.z + xa.w * yb.w;
  }
  G[id] = s * 0.044194173824159216f;
}

__global__ void kprep_Wvp(const float* __restrict__ Wv, const float* __restrict__ Wp,
                          u16* __restrict__ WvpT) {
  int id = blockIdx.x * 256 + threadIdx.x;  // 65536 : e*128+c
  int e = id >> 7, c = id & 127;
  float s = 0.f;
#pragma unroll 4
  for (int d = 0; d < 512; ++d) s += Wv[(size_t)c * 512 + d] * Wp[(size_t)d * 512 + e];
  WvpT[id] = f2bf(s);
}

__global__ void kprep_W1T(const float* __restrict__ W1, u16* __restrict__ W1T) {
  int id = blockIdx.x * 256 + threadIdx.x;  // 1M : f*512+e
  int f = id >> 9, e = id & 511;
  W1T[id] = f2bf(W1[(size_t)e * 2048 + f]);
}
__global__ void kprep_W2T(const float* __restrict__ W2, u16* __restrict__ W2T) {
  int id = blockIdx.x * 256 + threadIdx.x;  // 1M : e*2048+f
  int e = id >> 11, f = id & 2047;
  W2T[id] = f2bf(W2[(size_t)f * 512 + e]);
}

// ---------------- token attention: Z = softmax(mask(S G S^T)) S ----------------
__global__ __launch_bounds__(256) void ktoken(const float* __restrict__ x,
                                              const float* __restrict__ G,
                                              u16* __restrict__ Z) {
  __shared__ float Ss[4 * 512];
  __shared__ float T1s[4 * 512];
  __shared__ float Ws[4 * 16];
  int tid = threadIdx.x;
  int wave = tid >> 6, lane = tid & 63;
  int tok0 = blockIdx.x * 4;
  {
    const float4* xsrc = (const float4*)(x + (size_t)tok0 * 512);
    float4* sdst = (float4*)Ss;
    sdst[tid] = xsrc[tid];
    sdst[256 + tid] = xsrc[256 + tid];
  }
  __syncthreads();
  {
    const float* Sw = Ss + wave * 512;
    float a00 = 0, a01 = 0, a10 = 0, a11 = 0, a20 = 0, a21 = 0, a30 = 0, a31 = 0;
#pragma unroll 4
    for (int c = 0; c < 128; ++c) {
      float2 gg = ((const float2*)(G + (size_t)c * 128))[lane];
      float s0 = Sw[c], s1 = Sw[128 + c], s2 = Sw[256 + c], s3 = Sw[384 + c];
      a00 += s0 * gg.x; a01 += s0 * gg.y;
      a10 += s1 * gg.x; a11 += s1 * gg.y;
      a20 += s2 * gg.x; a21 += s2 * gg.y;
      a30 += s3 * gg.x; a31 += s3 * gg.y;
    }
    float* Tw = T1s + wave * 512;
    int c2 = lane * 2;
    Tw[c2] = a00; Tw[c2 + 1] = a01;
    Tw[128 + c2] = a10; Tw[128 + c2 + 1] = a11;
    Tw[256 + c2] = a20; Tw[256 + c2 + 1] = a21;
    Tw[384 + c2] = a30; Tw[384 + c2 + 1] = a31;
  }
  __syncthreads();
  if (lane < 16) {
    int i = lane >> 2, j = lane & 3;
    const float* Tw = T1s + wave * 512 + i * 128;
    const float* Sw = Ss + wave * 512 + j * 128;
    float d = 0.f;
#pragma unroll 8
    for (int c = 0; c < 128; ++c) d += Tw[c] * Sw[c];
    Ws[wave * 16 + i * 4 + j] = d;
  }
  __syncthreads();
  {
    float p[4][4];
    const float* ww = Ws + wave * 16;
#pragma unroll
    for (int i = 0; i < 4; ++i) {
      float m = -1e30f;
      for (int j = 0; j <= i; ++j) m = fmaxf(m, ww[i * 4 + j]);
      float s = 0.f;
      for (int j = 0; j <= i; ++j) { p[i][j] = __expf(ww[i * 4 + j] - m); s += p[i][j]; }
      float inv = 1.f / s;
      for (int j = 0; j <= i; ++j) p[i][j] *= inv;
      for (int j = i + 1; j < 4; ++j) p[i][j] = 0.f;
    }
    const float* Sw = Ss + wave * 512;
    int c = lane * 2;
    u32* zout = (u32*)(Z + (size_t)(tok0 + wave) * 512);
#pragma unroll
    for (int i = 0; i < 4; ++i) {
      float z0 = 0.f, z1 = 0.f;
#pragma unroll
      for (int j = 0; j < 4; ++j) {
        z0 += p[i][j] * Sw[j * 128 + c];
        z1 += p[i][j] * Sw[j * 128 + c + 1];
      }
      zout[i * 64 + lane] = (u32)f2bf(z0) | ((u32)f2bf(z1) << 16);
    }
  }
}

// ---------------- attn-out projection + bias + residual + LN1 -> X1 (bf16) ----------------
__global__ __launch_bounds__(512) void kattn(const u16* __restrict__ Z,
                                             const u16* __restrict__ WvpT,
                                             const float* __restrict__ bp,
                                             const float* __restrict__ x,
                                             const float* __restrict__ g1,
                                             const float* __restrict__ bln1,
                                             u16* __restrict__ X1) {
  __shared__ u16 AO[32768];
  __shared__ float rsum[64 * 4];
  __shared__ float rsq[64 * 4];
  __shared__ float mus[64];
  __shared__ float rss[64];
  char* smem = (char*)AO;
  int tid = threadIdx.x;
  int lane = tid & 63, wid = tid >> 6;
  int wm = wid >> 2, wnq = wid & 3;
  int lane_lo = lane & 15, lane_hi = lane >> 4;
  int m0 = blockIdx.x * 64;
  {
    const bf16x8* src = (const bf16x8*)(Z + (size_t)m0 * 128);
#pragma unroll
    for (int it = 0; it < 2; ++it) {
      int idx8 = it * 512 + tid;
      int row = idx8 >> 4;
      int byte = (idx8 * 16) ^ ((row & 7) << 4);
      *(bf16x8*)(smem + byte) = src[idx8];
    }
  }
  __syncthreads();
  f32x4 acc[2][8];
#pragma unroll
  for (int mi = 0; mi < 2; ++mi)
#pragma unroll
    for (int ni = 0; ni < 8; ++ni) acc[mi][ni] = (f32x4){0.f, 0.f, 0.f, 0.f};
#pragma unroll
  for (int ks = 0; ks < 4; ++ks) {
    bf16x8 af[2];
#pragma unroll
    for (int mi = 0; mi < 2; ++mi) {
      int row = wm * 32 + mi * 16 + lane_lo;
      int byte = (row * 256 + (ks * 32 + lane_hi * 8) * 2) ^ ((row & 7) << 4);
      af[mi] = *(const bf16x8*)(smem + byte);
    }
#pragma unroll
    for (int ni = 0; ni < 8; ++ni) {
      int n = wnq * 128 + ni * 16 + lane_lo;
      bf16x8 bfr = *(const bf16x8*)(WvpT + (size_t)n * 128 + ks * 32 + lane_hi * 8);
#pragma unroll
      for (int mi = 0; mi < 2; ++mi)
        acc[mi][ni] = __builtin_amdgcn_mfma_f32_16x16x32_bf16(af[mi], bfr, acc[mi][ni], 0, 0, 0);
    }
  }
#pragma unroll
  for (int mi = 0; mi < 2; ++mi) {
#pragma unroll
    for (int j = 0; j < 4; ++j) {
      int rl = wm * 32 + mi * 16 + lane_hi * 4 + j;
      int R = m0 + rl;
      const float* xrow = x + (size_t)(R >> 2) * 512;
      float s = 0.f, q = 0.f;
#pragma unroll
      for (int ni = 0; ni < 8; ++ni) {
        int col = wnq * 128 + ni * 16 + lane_lo;
        float val = acc[mi][ni][j] + bp[col] + xrow[col];
        acc[mi][ni][j] = val;
        s += val; q += val * val;
      }
#pragma unroll
      for (int off = 1; off < 16; off <<= 1) { s += __shfl_xor(s, off); q += __shfl_xor(q, off); }
      if (lane_lo == 0) { rsum[rl * 4 + wnq] = s; rsq[rl * 4 + wnq] = q; }
    }
  }
  __syncthreads();
  if (tid < 64) {
    float s = rsum[tid * 4] + rsum[tid * 4 + 1] + rsum[tid * 4 + 2] + rsum[tid * 4 + 3];
    float q = rsq[tid * 4] + rsq[tid * 4 + 1] + rsq[tid * 4 + 2] + rsq[tid * 4 + 3];
    float mu = s * (1.f / 512.f);
    float var = q * (1.f / 512.f) - mu * mu;
    mus[tid] = mu;
    rss[tid] = rsqrtf(var + 512.0f);
  }
  __syncthreads();
#pragma unroll
  for (int mi = 0; mi < 2; ++mi) {
#pragma unroll
    for (int j = 0; j < 4; ++j) {
      int rl = wm * 32 + mi * 16 + lane_hi * 4 + j;
      float mu = mus[rl], rs = rss[rl];
#pragma unroll
      for (int ni = 0; ni < 8; ++ni) {
        int col = wnq * 128 + ni * 16 + lane_lo;
        AO[rl * 512 + col] = f2bf((acc[mi][ni][j] - mu) * rs * g1[col] + bln1[col]);
      }
    }
  }
  __syncthreads();
  {
    bf16x8* dst = (bf16x8*)(X1 + (size_t)m0 * 512);
    const bf16x8* s8 = (const bf16x8*)AO;
#pragma unroll
    for (int it = 0; it < 8; ++it) dst[it * 512 + tid] = s8[it * 512 + tid];
  }
}

// ---------------- fused MLP with 3-buffer B-fragment register prefetch ----------------
// chunk = 16 slots: FF1 = 8 ks-pairs (slots 0-7), FF2 = 8 half-ks (slots 8-15).
// slot s consumes bq[s%3] (4 frags, 16 VGPR), issues loads for slot s+2 into bq[(s+2)%3]
// -> each L2 B-load gets ~2 slots (~200cy) head start. All indices compile-time (full unroll).
__device__ __forceinline__ void iss_f1(bf16x8 dst[4], const u16* w1base, int ch, int p) {
#pragma unroll
  for (int k = 0; k < 4; ++k) {
    int ksl = k >> 1, ni = k & 1;
    dst[k] = *(const bf16x8*)(w1base + (size_t)(ch * 128 + ni * 16) * 512 + (p * 2 + ksl) * 32);
  }
}
__device__ __forceinline__ void iss_f2(bf16x8 dst[4], const u16* w2base, int ch, int h) {
#pragma unroll
  for (int k = 0; k < 4; ++k) {
    dst[k] = *(const bf16x8*)(w2base + (size_t)((h & 1) * 64 + k * 16) * 2048 + ch * 128 + (h >> 1) * 32);
  }
}

__global__ __launch_bounds__(512) void kmlp(const u16* __restrict__ X1,
                                            const u16* __restrict__ W1T,
                                            const u16* __restrict__ W2T,
                                            const float* __restrict__ b1v,
                                            const float* __restrict__ b2v,
                                            const float* __restrict__ g2,
                                            const float* __restrict__ bln2,
                                            float* __restrict__ out) {
  __shared__ u16 Abuf[32768];  // 64KB: X1 tile [64][512] bf16, swizzled
  __shared__ u16 Hbuf[8192];   // 16KB: Hc [64][128] bf16, swizzled; stats aliased in epilogue
  char* Abase = (char*)Abuf;
  char* Hbase = (char*)Hbuf;
  float* rsum = (float*)Hbuf;
  float* rsq  = (float*)Hbuf + 256;
  float* mus  = (float*)Hbuf + 512;
  float* rss  = (float*)Hbuf + 576;
  int tid = threadIdx.x;
  int lane = tid & 63, wid = tid >> 6;
  int wm = wid >> 2, wnq = wid & 3;
  int lane_lo = lane & 15, lane_hi = lane >> 4;
  int m0 = blockIdx.x * 64;

  const u16* w1base = W1T + (size_t)(wnq * 32 + lane_lo) * 512 + lane_hi * 8;
  const u16* w2base = W2T + (size_t)(wnq * 128 + lane_lo) * 2048 + lane_hi * 8;

  // stage X1 tile (64x512 bf16 = 64KB), swizzled
  {
    const bf16x8* src = (const bf16x8*)(X1 + (size_t)m0 * 512);
#pragma unroll
    for (int it = 0; it < 8; ++it) {
      int idx8 = it * 512 + tid;
      int row = idx8 >> 6;
      int byte = (idx8 * 16) ^ ((row & 7) << 4);
      *(bf16x8*)(Abase + byte) = src[idx8];
    }
  }
  __syncthreads();

  f32x4 accO[2][8];
#pragma unroll
  for (int mi = 0; mi < 2; ++mi)
#pragma unroll
    for (int ni = 0; ni < 8; ++ni) accO[mi][ni] = (f32x4){0.f, 0.f, 0.f, 0.f};

  bf16x8 bq[3][4];

  for (int ch = 0; ch < 16; ++ch) {
    f32x4 acc1[2][2];
#pragma unroll
    for (int mi = 0; mi < 2; ++mi)
#pragma unroll
      for (int ni = 0; ni < 2; ++ni) acc1[mi][ni] = (f32x4){0.f, 0.f, 0.f, 0.f};

    // chunk-entry fill (slots 0 and 1)
    iss_f1(bq[0], w1base, ch, 0);
    iss_f1(bq[1], w1base, ch, 1);

    // FF1: 8 ks-pairs
#pragma unroll
    for (int p = 0; p < 8; ++p) {
      const int t = p % 3, nx = (p + 2) % 3;
      if (p < 6) iss_f1(bq[nx], w1base, ch, p + 2);
      else       iss_f2(bq[nx], w2base, ch, p - 6);   // FF2 halves 0,1 in flight over gelu
#pragma unroll
      for (int ksl = 0; ksl < 2; ++ksl) {
        int ks = p * 2 + ksl;
        bf16x8 af[2];
#pragma unroll
        for (int mi = 0; mi < 2; ++mi) {
          int row = wm * 32 + mi * 16 + lane_lo;
          int byte = (row * 1024 + (ks * 32 + lane_hi * 8) * 2) ^ ((row & 7) << 4);
          af[mi] = *(const bf16x8*)(Abase + byte);
        }
#pragma unroll
        for (int ni = 0; ni < 2; ++ni)
#pragma unroll
          for (int mi = 0; mi < 2; ++mi)
            acc1[mi][ni] = __builtin_amdgcn_mfma_f32_16x16x32_bf16(af[mi], bq[t][ksl * 2 + ni],
                                                                   acc1[mi][ni], 0, 0, 0);
      }
    }

    // gelu -> Hc (bf16, swizzled). Previous chunk's FF2 H-reads fenced by loop-end barrier.
#pragma unroll
    for (int mi = 0; mi < 2; ++mi)
#pragma unroll
      for (int ni = 0; ni < 2; ++ni)
#pragma unroll
        for (int j = 0; j < 4; ++j) {
          int rl = wm * 32 + mi * 16 + lane_hi * 4 + j;
          int col = wnq * 32 + ni * 16 + lane_lo;
          float u = acc1[mi][ni][j] + b1v[ch * 128 + col];
          float ge = 0.5f * u * (1.f + erff(u * 0.70710678118654752f));
          int byte = (rl * 256 + col * 2) ^ ((rl & 7) << 4);
          *(u16*)(Hbase + byte) = f2bf(ge);
        }
    __syncthreads();

    // FF2: 8 half-ks slots (slots 8..15)
    bf16x8 ah[2];
#pragma unroll
    for (int h = 0; h < 8; ++h) {
      const int s = 8 + h, t = s % 3, nx = (s + 2) % 3;
      if (h < 6) iss_f2(bq[nx], w2base, ch, h + 2);
      if ((h & 1) == 0) {
        int ks = h >> 1;
#pragma unroll
        for (int mi = 0; mi < 2; ++mi) {
          int row = wm * 32 + mi * 16 + lane_lo;
          int byte = (row * 256 + (ks * 32 + lane_hi * 8) * 2) ^ ((row & 7) << 4);
          ah[mi] = *(const bf16x8*)(Hbase + byte);
        }
      }
#pragma unroll
      for (int k = 0; k < 4; ++k) {
        int ni = (h & 1) * 4 + k;
#pragma unroll
        for (int mi = 0; mi < 2; ++mi)
          accO[mi][ni] = __builtin_amdgcn_mfma_f32_16x16x32_bf16(ah[mi], bq[t][k],
                                                                 accO[mi][ni], 0, 0, 0);
      }
    }
    __syncthreads();  // H reads done before next chunk's gelu overwrites (and stats alias)
  }

  // epilogue: + b2 + x1 residual, LN2, fp32 out
#pragma unroll
  for (int mi = 0; mi < 2; ++mi) {
#pragma unroll
    for (int j = 0; j < 4; ++j) {
      int rl = wm * 32 + mi * 16 + lane_hi * 4 + j;
      float s = 0.f, q = 0.f;
#pragma unroll
      for (int ni = 0; ni < 8; ++ni) {
        int col = wnq * 128 + ni * 16 + lane_lo;
        int abyte = (rl * 1024 + col * 2) ^ ((rl & 7) << 4);
        float x1v = bf2f(*(const u16*)(Abase + abyte));
        float val = accO[mi][ni][j] + b2v[col] + x1v;
        accO[mi][ni][j] = val;
        s += val; q += val * val;
      }
#pragma unroll
      for (int off = 1; off < 16; off <<= 1) { s += __shfl_xor(s, off); q += __shfl_xor(q, off); }
      if (lane_lo == 0) { rsum[rl * 4 + wnq] = s; rsq[rl * 4 + wnq] = q; }
    }
  }
  __syncthreads();
  if (tid < 64) {
    float s = rsum[tid * 4] + rsum[tid * 4 + 1] + rsum[tid * 4 + 2] + rsum[tid * 4 + 3];
    float q = rsq[tid * 4] + rsq[tid * 4 + 1] + rsq[tid * 4 + 2] + rsq[tid * 4 + 3];
    float mu = s * (1.f / 512.f);
    float var = q * (1.f / 512.f) - mu * mu;
    mus[tid] = mu;
    rss[tid] = rsqrtf(var + 512.0f);
  }
  __syncthreads();
#pragma unroll
  for (int mi = 0; mi < 2; ++mi) {
#pragma unroll
    for (int j = 0; j < 4; ++j) {
      int rl = wm * 32 + mi * 16 + lane_hi * 4 + j;
      float mu = mus[rl], rs = rss[rl];
      float* orow = out + (size_t)(m0 + rl) * 512;
#pragma unroll
      for (int ni = 0; ni < 8; ++ni) {
        int col = wnq * 128 + ni * 16 + lane_lo;
        orow[col] = (accO[mi][ni][j] - mu) * rs * g2[col] + bln2[col];
      }
    }
  }
}

extern "C" void kernel_launch(void* const* d_in, const int* in_sizes, int n_in,
                              void* d_out, int out_size, void* d_ws, size_t ws_size,
                              hipStream_t stream) {
  const float* x   = (const float*)d_in[0];
  const float* Wq  = (const float*)d_in[1];
  const float* Wk  = (const float*)d_in[2];
  const float* Wv  = (const float*)d_in[3];
  const float* Wp  = (const float*)d_in[4];
  const float* bp  = (const float*)d_in[5];
  const float* W1  = (const float*)d_in[6];
  const float* b1  = (const float*)d_in[7];
  const float* W2  = (const float*)d_in[8];
  const float* b2  = (const float*)d_in[9];
  const float* g1  = (const float*)d_in[10];
  const float* bb1 = (const float*)d_in[11];
  const float* g2  = (const float*)d_in[12];
  const float* bb2 = (const float*)d_in[13];
  float* out = (float*)d_out;

  char* ws = (char*)d_ws;
  float* G  = (float*)ws;                    // 64KB region (256KB reserved)
  u16* WvpT = (u16*)(ws + (256 << 10));      // 128KB
  u16* W1T  = (u16*)(ws + (1 << 20));        // 2MB
  u16* W2T  = (u16*)(ws + (3 << 20));        // 2MB
  u16* Z    = (u16*)(ws + (5 << 20));        // 16MB
  u16* X1   = (u16*)(ws + (21 << 20));       // 64MB

  hipLaunchKernelGGL(kprep_G,   dim3(64),   dim3(256), 0, stream, Wq, Wk, G);
  hipLaunchKernelGGL(kprep_Wvp, dim3(256),  dim3(256), 0, stream, Wv, Wp, WvpT);
  hipLaunchKernelGGL(kprep_W1T, dim3(4096), dim3(256), 0, stream, W1, W1T);
  hipLaunchKernelGGL(kprep_W2T, dim3(4096), dim3(256), 0, stream, W2, W2T);
  hipLaunchKernelGGL(ktoken,    dim3(4096), dim3(256), 0, stream, x, G, Z);
  hipLaunchKernelGGL(kattn,     dim3(1024), dim3(512), 0, stream, Z, WvpT, bp, x, g1, bb1, X1);
  hipLaunchKernelGGL(kmlp,      dim3(1024), dim3(512), 0, stream, X1, W1T, W2T, b1, b2, g2, bb2, out);
}

// Round 5
// 1259.087 us; speedup vs baseline: 1.0024x; 1.0024x over previous
//
#include <hip/hip_runtime.h>
#include <hip/hip_bf16.h>
#include <math.h>

typedef __bf16 bf16x8 __attribute__((ext_vector_type(8)));
typedef float f32x4 __attribute__((ext_vector_type(4)));
typedef unsigned short u16;
typedef unsigned int u32;

#define TOKENS 16384
#define MROWS  65536

#define SB()  __builtin_amdgcn_sched_barrier(0)
#define BAR() __builtin_amdgcn_s_barrier()
#define WAIT_LGKM() asm volatile("s_waitcnt lgkmcnt(0)" ::: "memory")

__device__ __forceinline__ u16 f2bf(float f) {
  union { __hip_bfloat16 h; u16 u; } c;
  c.h = __float2bfloat16(f);
  return c.u;
}
__device__ __forceinline__ float bf2f(u16 u) {
  union { u16 u; __hip_bfloat16 h; } c;
  c.u = u;
  return __bfloat162float(c.h);
}
// tanh-form gelu (~10 VALU ops vs ~40 for erff); |err| <= ~4e-4 in h, ~5e-6 on out
__device__ __forceinline__ float gelu_f(float u) {
  float y = 0.7978845608028654f * (u + 0.044715f * u * u * u);
  float e = __expf(2.f * y);
  float t = 1.f - 2.f / (e + 1.f);
  return 0.5f * u * (1.f + t);
}

// ---------------- prep kernels ----------------
__global__ void kprep_G(const float* __restrict__ Wq, const float* __restrict__ Wk,
                        float* __restrict__ G) {
  int id = blockIdx.x * 256 + threadIdx.x;  // 16384
  int c = id >> 7, c2 = id & 127;
  const float4* a = (const float4*)(Wq + (size_t)c * 512);
  const float4* b = (const float4*)(Wk + (size_t)c2 * 512);
  float s = 0.f;
#pragma unroll 8
  for (int i = 0; i < 128; ++i) {
    float4 xa = a[i], yb = b[i];
    s += xa.x * yb.x + xa.y * yb.y + xa.z * yb.z + xa.w * yb.w;
  }
  G[id] = s * 0.044194173824159216f;
}

__global__ void kprep_Wvp(const float* __restrict__ Wv, const float* __restrict__ Wp,
                          u16* __restrict__ WvpT) {
  int id = blockIdx.x * 256 + threadIdx.x;  // 65536 : e*128+c
  int e = id >> 7, c = id & 127;
  float s = 0.f;
#pragma unroll 4
  for (int d = 0; d < 512; ++d) s += Wv[(size_t)c * 512 + d] * Wp[(size_t)d * 512 + e];
  WvpT[id] = f2bf(s);
}

__global__ void kprep_W1T(const float* __restrict__ W1, u16* __restrict__ W1T) {
  int id = blockIdx.x * 256 + threadIdx.x;  // 1M : f*512+e
  int f = id >> 9, e = id & 511;
  W1T[id] = f2bf(W1[(size_t)e * 2048 + f]);
}
__global__ void kprep_W2T(const float* __restrict__ W2, u16* __restrict__ W2T) {
  int id = blockIdx.x * 256 + threadIdx.x;  // 1M : e*2048+f
  int e = id >> 11, f = id & 2047;
  W2T[id] = f2bf(W2[(size_t)f * 512 + e]);
}

// ---------------- token attention: Z = softmax(mask(S G S^T)) S ----------------
__global__ __launch_bounds__(256) void ktoken(const float* __restrict__ x,
                                              const float* __restrict__ G,
                                              u16* __restrict__ Z) {
  __shared__ float Ss[4 * 512];
  __shared__ float T1s[4 * 512];
  __shared__ float Ws[4 * 16];
  int tid = threadIdx.x;
  int wave = tid >> 6, lane = tid & 63;
  int tok0 = blockIdx.x * 4;
  {
    const float4* xsrc = (const float4*)(x + (size_t)tok0 * 512);
    float4* sdst = (float4*)Ss;
    sdst[tid] = xsrc[tid];
    sdst[256 + tid] = xsrc[256 + tid];
  }
  __syncthreads();
  {
    const float* Sw = Ss + wave * 512;
    float a00 = 0, a01 = 0, a10 = 0, a11 = 0, a20 = 0, a21 = 0, a30 = 0, a31 = 0;
#pragma unroll 4
    for (int c = 0; c < 128; ++c) {
      float2 gg = ((const float2*)(G + (size_t)c * 128))[lane];
      float s0 = Sw[c], s1 = Sw[128 + c], s2 = Sw[256 + c], s3 = Sw[384 + c];
      a00 += s0 * gg.x; a01 += s0 * gg.y;
      a10 += s1 * gg.x; a11 += s1 * gg.y;
      a20 += s2 * gg.x; a21 += s2 * gg.y;
      a30 += s3 * gg.x; a31 += s3 * gg.y;
    }
    float* Tw = T1s + wave * 512;
    int c2 = lane * 2;
    Tw[c2] = a00; Tw[c2 + 1] = a01;
    Tw[128 + c2] = a10; Tw[128 + c2 + 1] = a11;
    Tw[256 + c2] = a20; Tw[256 + c2 + 1] = a21;
    Tw[384 + c2] = a30; Tw[384 + c2 + 1] = a31;
  }
  __syncthreads();
  if (lane < 16) {
    int i = lane >> 2, j = lane & 3;
    const float* Tw = T1s + wave * 512 + i * 128;
    const float* Sw = Ss + wave * 512 + j * 128;
    float d = 0.f;
#pragma unroll 8
    for (int c = 0; c < 128; ++c) d += Tw[c] * Sw[c];
    Ws[wave * 16 + i * 4 + j] = d;
  }
  __syncthreads();
  {
    float p[4][4];
    const float* ww = Ws + wave * 16;
#pragma unroll
    for (int i = 0; i < 4; ++i) {
      float m = -1e30f;
      for (int j = 0; j <= i; ++j) m = fmaxf(m, ww[i * 4 + j]);
      float s = 0.f;
      for (int j = 0; j <= i; ++j) { p[i][j] = __expf(ww[i * 4 + j] - m); s += p[i][j]; }
      float inv = 1.f / s;
      for (int j = 0; j <= i; ++j) p[i][j] *= inv;
      for (int j = i + 1; j < 4; ++j) p[i][j] = 0.f;
    }
    const float* Sw = Ss + wave * 512;
    int c = lane * 2;
    u32* zout = (u32*)(Z + (size_t)(tok0 + wave) * 512);
#pragma unroll
    for (int i = 0; i < 4; ++i) {
      float z0 = 0.f, z1 = 0.f;
#pragma unroll
      for (int j = 0; j < 4; ++j) {
        z0 += p[i][j] * Sw[j * 128 + c];
        z1 += p[i][j] * Sw[j * 128 + c + 1];
      }
      zout[i * 64 + lane] = (u32)f2bf(z0) | ((u32)f2bf(z1) << 16);
    }
  }
}

// ---------------- attn-out projection + bias + residual + LN1 -> X1 (bf16) ----------------
__global__ __launch_bounds__(512) void kattn(const u16* __restrict__ Z,
                                             const u16* __restrict__ WvpT,
                                             const float* __restrict__ bp,
                                             const float* __restrict__ x,
                                             const float* __restrict__ g1,
                                             const float* __restrict__ bln1,
                                             u16* __restrict__ X1) {
  __shared__ u16 AO[32768];
  __shared__ float rsum[64 * 4];
  __shared__ float rsq[64 * 4];
  __shared__ float mus[64];
  __shared__ float rss[64];
  char* smem = (char*)AO;
  int tid = threadIdx.x;
  int lane = tid & 63, wid = tid >> 6;
  int wm = wid >> 2, wnq = wid & 3;
  int lane_lo = lane & 15, lane_hi = lane >> 4;
  int m0 = blockIdx.x * 64;
  {
    const bf16x8* src = (const bf16x8*)(Z + (size_t)m0 * 128);
#pragma unroll
    for (int it = 0; it < 2; ++it) {
      int idx8 = it * 512 + tid;
      int row = idx8 >> 4;
      int byte = (idx8 * 16) ^ ((row & 7) << 4);
      *(bf16x8*)(smem + byte) = src[idx8];
    }
  }
  __syncthreads();
  f32x4 acc[2][8];
#pragma unroll
  for (int mi = 0; mi < 2; ++mi)
#pragma unroll
    for (int ni = 0; ni < 8; ++ni) acc[mi][ni] = (f32x4){0.f, 0.f, 0.f, 0.f};
#pragma unroll
  for (int ks = 0; ks < 4; ++ks) {
    bf16x8 af[2];
#pragma unroll
    for (int mi = 0; mi < 2; ++mi) {
      int row = wm * 32 + mi * 16 + lane_lo;
      int byte = (row * 256 + (ks * 32 + lane_hi * 8) * 2) ^ ((row & 7) << 4);
      af[mi] = *(const bf16x8*)(smem + byte);
    }
#pragma unroll
    for (int ni = 0; ni < 8; ++ni) {
      int n = wnq * 128 + ni * 16 + lane_lo;
      bf16x8 bfr = *(const bf16x8*)(WvpT + (size_t)n * 128 + ks * 32 + lane_hi * 8);
#pragma unroll
      for (int mi = 0; mi < 2; ++mi)
        acc[mi][ni] = __builtin_amdgcn_mfma_f32_16x16x32_bf16(af[mi], bfr, acc[mi][ni], 0, 0, 0);
    }
  }
#pragma unroll
  for (int mi = 0; mi < 2; ++mi) {
#pragma unroll
    for (int j = 0; j < 4; ++j) {
      int rl = wm * 32 + mi * 16 + lane_hi * 4 + j;
      int R = m0 + rl;
      const float* xrow = x + (size_t)(R >> 2) * 512;
      float s = 0.f, q = 0.f;
#pragma unroll
      for (int ni = 0; ni < 8; ++ni) {
        int col = wnq * 128 + ni * 16 + lane_lo;
        float val = acc[mi][ni][j] + bp[col] + xrow[col];
        acc[mi][ni][j] = val;
        s += val; q += val * val;
      }
#pragma unroll
      for (int off = 1; off < 16; off <<= 1) { s += __shfl_xor(s, off); q += __shfl_xor(q, off); }
      if (lane_lo == 0) { rsum[rl * 4 + wnq] = s; rsq[rl * 4 + wnq] = q; }
    }
  }
  __syncthreads();
  if (tid < 64) {
    float s = rsum[tid * 4] + rsum[tid * 4 + 1] + rsum[tid * 4 + 2] + rsum[tid * 4 + 3];
    float q = rsq[tid * 4] + rsq[tid * 4 + 1] + rsq[tid * 4 + 2] + rsq[tid * 4 + 3];
    float mu = s * (1.f / 512.f);
    float var = q * (1.f / 512.f) - mu * mu;
    mus[tid] = mu;
    rss[tid] = rsqrtf(var + 512.0f);
  }
  __syncthreads();
#pragma unroll
  for (int mi = 0; mi < 2; ++mi) {
#pragma unroll
    for (int j = 0; j < 4; ++j) {
      int rl = wm * 32 + mi * 16 + lane_hi * 4 + j;
      float mu = mus[rl], rs = rss[rl];
#pragma unroll
      for (int ni = 0; ni < 8; ++ni) {
        int col = wnq * 128 + ni * 16 + lane_lo;
        AO[rl * 512 + col] = f2bf((acc[mi][ni][j] - mu) * rs * g1[col] + bln1[col]);
      }
    }
  }
  __syncthreads();
  {
    bf16x8* dst = (bf16x8*)(X1 + (size_t)m0 * 512);
    const bf16x8* s8 = (const bf16x8*)AO;
#pragma unroll
    for (int it = 0; it < 8; ++it) dst[it * 512 + tid] = s8[it * 512 + tid];
  }
}

// ---------------- fused MLP: ring-4 pinned B prefetch + raw barriers ----------------
// 16 slots/chunk (FF1 8 ks-pairs, FF2 8 half-ks). Slot S consumes bq[S&3], then
// refills bq[S&3] for slot S+4 (WAR stops hoist; sched_barrier(0) stops sinking).
// Queue stays in flight across the gelu barrier (raw s_barrier, no vmcnt drain).
__device__ __forceinline__ void iss_f1(bf16x8 dst[4], const u16* w1base, int ch, int p) {
#pragma unroll
  for (int k = 0; k < 4; ++k) {
    int ksl = k >> 1, ni = k & 1;
    dst[k] = *(const bf16x8*)(w1base + (size_t)(ch * 128 + ni * 16) * 512 + (p * 2 + ksl) * 32);
  }
}
__device__ __forceinline__ void iss_f2(bf16x8 dst[4], const u16* w2base, int ch, int h) {
#pragma unroll
  for (int k = 0; k < 4; ++k) {
    dst[k] = *(const bf16x8*)(w2base + (size_t)((h & 1) * 64 + k * 16) * 2048 + ch * 128 + (h >> 1) * 32);
  }
}

__global__ __launch_bounds__(512) void kmlp(const u16* __restrict__ X1,
                                            const u16* __restrict__ W1T,
                                            const u16* __restrict__ W2T,
                                            const float* __restrict__ b1v,
                                            const float* __restrict__ b2v,
                                            const float* __restrict__ g2,
                                            const float* __restrict__ bln2,
                                            float* __restrict__ out) {
  __shared__ u16 Abuf[32768];  // 64KB: X1 tile [64][512] bf16, swizzled
  __shared__ u16 Hbuf[8192];   // 16KB: Hc [64][128] bf16, swizzled; stats aliased in epilogue
  char* Abase = (char*)Abuf;
  char* Hbase = (char*)Hbuf;
  float* rsum = (float*)Hbuf;
  float* rsq  = (float*)Hbuf + 256;
  float* mus  = (float*)Hbuf + 512;
  float* rss  = (float*)Hbuf + 576;
  int tid = threadIdx.x;
  int lane = tid & 63, wid = tid >> 6;
  int wm = wid >> 2, wnq = wid & 3;
  int lane_lo = lane & 15, lane_hi = lane >> 4;
  int m0 = blockIdx.x * 64;

  const u16* w1base = W1T + (size_t)(wnq * 32 + lane_lo) * 512 + lane_hi * 8;
  const u16* w2base = W2T + (size_t)(wnq * 128 + lane_lo) * 2048 + lane_hi * 8;

  bf16x8 bq[4][4];
  // prologue: fill ring for ch0 FF1 slots 0-3 (16 loads in flight)
  iss_f1(bq[0], w1base, 0, 0);
  iss_f1(bq[1], w1base, 0, 1);
  iss_f1(bq[2], w1base, 0, 2);
  iss_f1(bq[3], w1base, 0, 3);
  SB();

  // stage X1 tile (64x512 bf16 = 64KB), swizzled — queue survives (raw barrier)
  {
    const bf16x8* src = (const bf16x8*)(X1 + (size_t)m0 * 512);
#pragma unroll
    for (int it = 0; it < 8; ++it) {
      int idx8 = it * 512 + tid;
      int row = idx8 >> 6;
      int byte = (idx8 * 16) ^ ((row & 7) << 4);
      *(bf16x8*)(Abase + byte) = src[idx8];
    }
  }
  WAIT_LGKM();
  SB();
  BAR();

  f32x4 accO[2][8];
#pragma unroll
  for (int mi = 0; mi < 2; ++mi)
#pragma unroll
    for (int ni = 0; ni < 8; ++ni) accO[mi][ni] = (f32x4){0.f, 0.f, 0.f, 0.f};

  for (int ch = 0; ch < 16; ++ch) {
    f32x4 acc1[2][2];
#pragma unroll
    for (int mi = 0; mi < 2; ++mi)
#pragma unroll
      for (int ni = 0; ni < 2; ++ni) acc1[mi][ni] = (f32x4){0.f, 0.f, 0.f, 0.f};

    // FF1: slots 0-7 (ks pairs)
#pragma unroll
    for (int p = 0; p < 8; ++p) {
#pragma unroll
      for (int ksl = 0; ksl < 2; ++ksl) {
        int ks = p * 2 + ksl;
        bf16x8 af[2];
#pragma unroll
        for (int mi = 0; mi < 2; ++mi) {
          int row = wm * 32 + mi * 16 + lane_lo;
          int byte = (row * 1024 + (ks * 32 + lane_hi * 8) * 2) ^ ((row & 7) << 4);
          af[mi] = *(const bf16x8*)(Abase + byte);
        }
#pragma unroll
        for (int ni = 0; ni < 2; ++ni)
#pragma unroll
          for (int mi = 0; mi < 2; ++mi)
            acc1[mi][ni] = __builtin_amdgcn_mfma_f32_16x16x32_bf16(af[mi], bq[p & 3][ksl * 2 + ni],
                                                                   acc1[mi][ni], 0, 0, 0);
      }
      // refill ring for slot p+4
      if (p < 4) iss_f1(bq[p & 3], w1base, ch, p + 4);
      else       iss_f2(bq[p & 3], w2base, ch, p - 4);  // FF2 h=0..3
      SB();
    }

    // gelu -> Hc (bf16, swizzled)
#pragma unroll
    for (int mi = 0; mi < 2; ++mi)
#pragma unroll
      for (int ni = 0; ni < 2; ++ni)
#pragma unroll
        for (int j = 0; j < 4; ++j) {
          int rl = wm * 32 + mi * 16 + lane_hi * 4 + j;
          int col = wnq * 32 + ni * 16 + lane_lo;
          float u = acc1[mi][ni][j] + b1v[ch * 128 + col];
          float ge = gelu_f(u);
          int byte = (rl * 256 + col * 2) ^ ((rl & 7) << 4);
          *(u16*)(Hbase + byte) = f2bf(ge);
        }
    WAIT_LGKM();   // H writes visible; vmcnt queue stays in flight
    SB();
    BAR();

    // FF2: slots 8-15 (half-ks)
    bf16x8 ah[2];
#pragma unroll
    for (int h = 0; h < 8; ++h) {
      if ((h & 1) == 0) {
        int ks = h >> 1;
#pragma unroll
        for (int mi = 0; mi < 2; ++mi) {
          int row = wm * 32 + mi * 16 + lane_lo;
          int byte = (row * 256 + (ks * 32 + lane_hi * 8) * 2) ^ ((row & 7) << 4);
          ah[mi] = *(const bf16x8*)(Hbase + byte);
        }
      }
#pragma unroll
      for (int k = 0; k < 4; ++k) {
        int ni = (h & 1) * 4 + k;
#pragma unroll
        for (int mi = 0; mi < 2; ++mi)
          accO[mi][ni] = __builtin_amdgcn_mfma_f32_16x16x32_bf16(ah[mi], bq[h & 3][k],
                                                                 accO[mi][ni], 0, 0, 0);
      }
      // refill: h<4 -> this chunk's FF2 h+4; h>=4 -> next chunk's FF1 p=h-4
      if (h < 4)        iss_f2(bq[h & 3], w2base, ch, h + 4);
      else if (ch < 15) iss_f1(bq[h & 3], w1base, ch + 1, h - 4);
      SB();
    }
    SB();
    BAR();  // all waves' H reads done before next gelu overwrites (and stats alias)
  }

  // epilogue: + b2 + x1 residual, LN2, fp32 out  (queue empty here)
#pragma unroll
  for (int mi = 0; mi < 2; ++mi) {
#pragma unroll
    for (int j = 0; j < 4; ++j) {
      int rl = wm * 32 + mi * 16 + lane_hi * 4 + j;
      float s = 0.f, q = 0.f;
#pragma unroll
      for (int ni = 0; ni < 8; ++ni) {
        int col = wnq * 128 + ni * 16 + lane_lo;
        int abyte = (rl * 1024 + col * 2) ^ ((rl & 7) << 4);
        float x1v = bf2f(*(const u16*)(Abase + abyte));
        float val = accO[mi][ni][j] + b2v[col] + x1v;
        accO[mi][ni][j] = val;
        s += val; q += val * val;
      }
#pragma unroll
      for (int off = 1; off < 16; off <<= 1) { s += __shfl_xor(s, off); q += __shfl_xor(q, off); }
      if (lane_lo == 0) { rsum[rl * 4 + wnq] = s; rsq[rl * 4 + wnq] = q; }
    }
  }
  __syncthreads();
  if (tid < 64) {
    float s = rsum[tid * 4] + rsum[tid * 4 + 1] + rsum[tid * 4 + 2] + rsum[tid * 4 + 3];
    float q = rsq[tid * 4] + rsq[tid * 4 + 1] + rsq[tid * 4 + 2] + rsq[tid * 4 + 3];
    float mu = s * (1.f / 512.f);
    float var = q * (1.f / 512.f) - mu * mu;
    mus[tid] = mu;
    rss[tid] = rsqrtf(var + 512.0f);
  }
  __syncthreads();
#pragma unroll
  for (int mi = 0; mi < 2; ++mi) {
#pragma unroll
    for (int j = 0; j < 4; ++j) {
      int rl = wm * 32 + mi * 16 + lane_hi * 4 + j;
      float mu = mus[rl], rs = rss[rl];
      float* orow = out + (size_t)(m0 + rl) * 512;
#pragma unroll
      for (int ni = 0; ni < 8; ++ni) {
        int col = wnq * 128 + ni * 16 + lane_lo;
        orow[col] = (accO[mi][ni][j] - mu) * rs * g2[col] + bln2[col];
      }
    }
  }
}

extern "C" void kernel_launch(void* const* d_in, const int* in_sizes, int n_in,
                              void* d_out, int out_size, void* d_ws, size_t ws_size,
                              hipStream_t stream) {
  const float* x   = (const float*)d_in[0];
  const float* Wq  = (const float*)d_in[1];
  const float* Wk  = (const float*)d_in[2];
  const float* Wv  = (const float*)d_in[3];
  const float* Wp  = (const float*)d_in[4];
  const float* bp  = (const float*)d_in[5];
  const float* W1  = (const float*)d_in[6];
  const float* b1  = (const float*)d_in[7];
  const float* W2  = (const float*)d_in[8];
  const float* b2  = (const float*)d_in[9];
  const float* g1  = (const float*)d_in[10];
  const float* bb1 = (const float*)d_in[11];
  const float* g2  = (const float*)d_in[12];
  const float* bb2 = (const float*)d_in[13];
  float* out = (float*)d_out;

  char* ws = (char*)d_ws;
  float* G  = (float*)ws;                    // 64KB region (256KB reserved)
  u16* WvpT = (u16*)(ws + (256 << 10));      // 128KB
  u16* W1T  = (u16*)(ws + (1 << 20));        // 2MB
  u16* W2T  = (u16*)(ws + (3 << 20));        // 2MB
  u16* Z    = (u16*)(ws + (5 << 20));        // 16MB
  u16* X1   = (u16*)(ws + (21 << 20));       // 64MB

  hipLaunchKernelGGL(kprep_G,   dim3(64),   dim3(256), 0, stream, Wq, Wk, G);
  hipLaunchKernelGGL(kprep_Wvp, dim3(256),  dim3(256), 0, stream, Wv, Wp, WvpT);
  hipLaunchKernelGGL(kprep_W1T, dim3(4096), dim3(256), 0, stream, W1, W1T);
  hipLaunchKernelGGL(kprep_W2T, dim3(4096), dim3(256), 0, stream, W2, W2T);
  hipLaunchKernelGGL(ktoken,    dim3(4096), dim3(256), 0, stream, x, G, Z);
  hipLaunchKernelGGL(kattn,     dim3(1024), dim3(512), 0, stream, Z, WvpT, bp, x, g1, bb1, X1);
  hipLaunchKernelGGL(kmlp,      dim3(1024), dim3(512), 0, stream, X1, W1T, W2T, b1, b2, g2, bb2, out);
}

// Round 6
// 804.829 us; speedup vs baseline: 1.5681x; 1.5644x over previous
//
#include <hip/hip_runtime.h>
#include <hip/hip_bf16.h>
#include <math.h>

typedef __bf16 bf16x8 __attribute__((ext_vector_type(8)));
typedef float f32x4 __attribute__((ext_vector_type(4)));
typedef unsigned short u16;
typedef unsigned int u32;

#define TOKENS 16384
#define MROWS  65536

#define SB()  __builtin_amdgcn_sched_barrier(0)
#define BAR() __builtin_amdgcn_s_barrier()
#define WAIT_LGKM() asm volatile("s_waitcnt lgkmcnt(0)" ::: "memory")

__device__ __forceinline__ u16 f2bf(float f) {
  union { __hip_bfloat16 h; u16 u; } c;
  c.h = __float2bfloat16(f);
  return c.u;
}
__device__ __forceinline__ float bf2f(u16 u) {
  union { u16 u; __hip_bfloat16 h; } c;
  c.u = u;
  return __bfloat162float(c.h);
}
// tanh-form gelu; validated in rounds 5 (absmax unchanged at 6.1e-5)
__device__ __forceinline__ float gelu_f(float u) {
  float y = 0.7978845608028654f * (u + 0.044715f * u * u * u);
  float e = __expf(2.f * y);
  float t = 1.f - 2.f / (e + 1.f);
  return 0.5f * u * (1.f + t);
}
// async global->LDS, 16B per lane; LDS dest is wave-uniform base + lane*16
__device__ __forceinline__ void gload16(const void* g, void* l) {
  __builtin_amdgcn_global_load_lds(
      (const __attribute__((address_space(1))) void*)g,
      (__attribute__((address_space(3))) void*)l, 16, 0, 0);
}

// ---------------- prep kernels ----------------
__global__ void kprep_G(const float* __restrict__ Wq, const float* __restrict__ Wk,
                        float* __restrict__ G) {
  int id = blockIdx.x * 256 + threadIdx.x;  // 16384
  int c = id >> 7, c2 = id & 127;
  const float4* a = (const float4*)(Wq + (size_t)c * 512);
  const float4* b = (const float4*)(Wk + (size_t)c2 * 512);
  float s = 0.f;
#pragma unroll 8
  for (int i = 0; i < 128; ++i) {
    float4 xa = a[i], yb = b[i];
    s += xa.x * yb.x + xa.y * yb.y + xa.z * yb.z + xa.w * yb.w;
  }
  G[id] = s * 0.044194173824159216f;
}

__global__ void kprep_Wvp(const float* __restrict__ Wv, const float* __restrict__ Wp,
                          u16* __restrict__ WvpT) {
  int id = blockIdx.x * 256 + threadIdx.x;  // 65536 : e*128+c
  int e = id >> 7, c = id & 127;
  float s = 0.f;
#pragma unroll 4
  for (int d = 0; d < 512; ++d) s += Wv[(size_t)c * 512 + d] * Wp[(size_t)d * 512 + e];
  WvpT[id] = f2bf(s);
}

__global__ void kprep_W1T(const float* __restrict__ W1, u16* __restrict__ W1T) {
  int id = blockIdx.x * 256 + threadIdx.x;  // 1M : f*512+e
  int f = id >> 9, e = id & 511;
  W1T[id] = f2bf(W1[(size_t)e * 2048 + f]);
}
__global__ void kprep_W2T(const float* __restrict__ W2, u16* __restrict__ W2T) {
  int id = blockIdx.x * 256 + threadIdx.x;  // 1M : e*2048+f
  int e = id >> 11, f = id & 2047;
  W2T[id] = f2bf(W2[(size_t)f * 512 + e]);
}

// ---------------- token attention: Z = softmax(mask(S G S^T)) S ----------------
__global__ __launch_bounds__(256) void ktoken(const float* __restrict__ x,
                                              const float* __restrict__ G,
                                              u16* __restrict__ Z) {
  __shared__ float Ss[4 * 512];
  __shared__ float T1s[4 * 512];
  __shared__ float Ws[4 * 16];
  int tid = threadIdx.x;
  int wave = tid >> 6, lane = tid & 63;
  int tok0 = blockIdx.x * 4;
  {
    const float4* xsrc = (const float4*)(x + (size_t)tok0 * 512);
    float4* sdst = (float4*)Ss;
    sdst[tid] = xsrc[tid];
    sdst[256 + tid] = xsrc[256 + tid];
  }
  __syncthreads();
  {
    const float* Sw = Ss + wave * 512;
    float a00 = 0, a01 = 0, a10 = 0, a11 = 0, a20 = 0, a21 = 0, a30 = 0, a31 = 0;
#pragma unroll 4
    for (int c = 0; c < 128; ++c) {
      float2 gg = ((const float2*)(G + (size_t)c * 128))[lane];
      float s0 = Sw[c], s1 = Sw[128 + c], s2 = Sw[256 + c], s3 = Sw[384 + c];
      a00 += s0 * gg.x; a01 += s0 * gg.y;
      a10 += s1 * gg.x; a11 += s1 * gg.y;
      a20 += s2 * gg.x; a21 += s2 * gg.y;
      a30 += s3 * gg.x; a31 += s3 * gg.y;
    }
    float* Tw = T1s + wave * 512;
    int c2 = lane * 2;
    Tw[c2] = a00; Tw[c2 + 1] = a01;
    Tw[128 + c2] = a10; Tw[128 + c2 + 1] = a11;
    Tw[256 + c2] = a20; Tw[256 + c2 + 1] = a21;
    Tw[384 + c2] = a30; Tw[384 + c2 + 1] = a31;
  }
  __syncthreads();
  if (lane < 16) {
    int i = lane >> 2, j = lane & 3;
    const float* Tw = T1s + wave * 512 + i * 128;
    const float* Sw = Ss + wave * 512 + j * 128;
    float d = 0.f;
#pragma unroll 8
    for (int c = 0; c < 128; ++c) d += Tw[c] * Sw[c];
    Ws[wave * 16 + i * 4 + j] = d;
  }
  __syncthreads();
  {
    float p[4][4];
    const float* ww = Ws + wave * 16;
#pragma unroll
    for (int i = 0; i < 4; ++i) {
      float m = -1e30f;
      for (int j = 0; j <= i; ++j) m = fmaxf(m, ww[i * 4 + j]);
      float s = 0.f;
      for (int j = 0; j <= i; ++j) { p[i][j] = __expf(ww[i * 4 + j] - m); s += p[i][j]; }
      float inv = 1.f / s;
      for (int j = 0; j <= i; ++j) p[i][j] *= inv;
      for (int j = i + 1; j < 4; ++j) p[i][j] = 0.f;
    }
    const float* Sw = Ss + wave * 512;
    int c = lane * 2;
    u32* zout = (u32*)(Z + (size_t)(tok0 + wave) * 512);
#pragma unroll
    for (int i = 0; i < 4; ++i) {
      float z0 = 0.f, z1 = 0.f;
#pragma unroll
      for (int j = 0; j < 4; ++j) {
        z0 += p[i][j] * Sw[j * 128 + c];
        z1 += p[i][j] * Sw[j * 128 + c + 1];
      }
      zout[i * 64 + lane] = (u32)f2bf(z0) | ((u32)f2bf(z1) << 16);
    }
  }
}

// ---------------- attn-out projection + bias + residual + LN1 -> X1 (bf16) ----------------
__global__ __launch_bounds__(512) void kattn(const u16* __restrict__ Z,
                                             const u16* __restrict__ WvpT,
                                             const float* __restrict__ bp,
                                             const float* __restrict__ x,
                                             const float* __restrict__ g1,
                                             const float* __restrict__ bln1,
                                             u16* __restrict__ X1) {
  __shared__ u16 AO[32768];
  __shared__ float rsum[64 * 4];
  __shared__ float rsq[64 * 4];
  __shared__ float mus[64];
  __shared__ float rss[64];
  char* smem = (char*)AO;
  int tid = threadIdx.x;
  int lane = tid & 63, wid = tid >> 6;
  int wm = wid >> 2, wnq = wid & 3;
  int lane_lo = lane & 15, lane_hi = lane >> 4;
  int m0 = blockIdx.x * 64;
  {
    const bf16x8* src = (const bf16x8*)(Z + (size_t)m0 * 128);
#pragma unroll
    for (int it = 0; it < 2; ++it) {
      int idx8 = it * 512 + tid;
      int row = idx8 >> 4;
      int byte = (idx8 * 16) ^ ((row & 7) << 4);
      *(bf16x8*)(smem + byte) = src[idx8];
    }
  }
  __syncthreads();
  f32x4 acc[2][8];
#pragma unroll
  for (int mi = 0; mi < 2; ++mi)
#pragma unroll
    for (int ni = 0; ni < 8; ++ni) acc[mi][ni] = (f32x4){0.f, 0.f, 0.f, 0.f};
#pragma unroll
  for (int ks = 0; ks < 4; ++ks) {
    bf16x8 af[2];
#pragma unroll
    for (int mi = 0; mi < 2; ++mi) {
      int row = wm * 32 + mi * 16 + lane_lo;
      int byte = (row * 256 + (ks * 32 + lane_hi * 8) * 2) ^ ((row & 7) << 4);
      af[mi] = *(const bf16x8*)(smem + byte);
    }
#pragma unroll
    for (int ni = 0; ni < 8; ++ni) {
      int n = wnq * 128 + ni * 16 + lane_lo;
      bf16x8 bfr = *(const bf16x8*)(WvpT + (size_t)n * 128 + ks * 32 + lane_hi * 8);
#pragma unroll
      for (int mi = 0; mi < 2; ++mi)
        acc[mi][ni] = __builtin_amdgcn_mfma_f32_16x16x32_bf16(af[mi], bfr, acc[mi][ni], 0, 0, 0);
    }
  }
#pragma unroll
  for (int mi = 0; mi < 2; ++mi) {
#pragma unroll
    for (int j = 0; j < 4; ++j) {
      int rl = wm * 32 + mi * 16 + lane_hi * 4 + j;
      int R = m0 + rl;
      const float* xrow = x + (size_t)(R >> 2) * 512;
      float s = 0.f, q = 0.f;
#pragma unroll
      for (int ni = 0; ni < 8; ++ni) {
        int col = wnq * 128 + ni * 16 + lane_lo;
        float val = acc[mi][ni][j] + bp[col] + xrow[col];
        acc[mi][ni][j] = val;
        s += val; q += val * val;
      }
#pragma unroll
      for (int off = 1; off < 16; off <<= 1) { s += __shfl_xor(s, off); q += __shfl_xor(q, off); }
      if (lane_lo == 0) { rsum[rl * 4 + wnq] = s; rsq[rl * 4 + wnq] = q; }
    }
  }
  __syncthreads();
  if (tid < 64) {
    float s = rsum[tid * 4] + rsum[tid * 4 + 1] + rsum[tid * 4 + 2] + rsum[tid * 4 + 3];
    float q = rsq[tid * 4] + rsq[tid * 4 + 1] + rsq[tid * 4 + 2] + rsq[tid * 4 + 3];
    float mu = s * (1.f / 512.f);
    float var = q * (1.f / 512.f) - mu * mu;
    mus[tid] = mu;
    rss[tid] = rsqrtf(var + 512.0f);
  }
  __syncthreads();
#pragma unroll
  for (int mi = 0; mi < 2; ++mi) {
#pragma unroll
    for (int j = 0; j < 4; ++j) {
      int rl = wm * 32 + mi * 16 + lane_hi * 4 + j;
      float mu = mus[rl], rs = rss[rl];
#pragma unroll
      for (int ni = 0; ni < 8; ++ni) {
        int col = wnq * 128 + ni * 16 + lane_lo;
        AO[rl * 512 + col] = f2bf((acc[mi][ni][j] - mu) * rs * g1[col] + bln1[col]);
      }
    }
  }
  __syncthreads();
  {
    bf16x8* dst = (bf16x8*)(X1 + (size_t)m0 * 512);
    const bf16x8* s8 = (const bf16x8*)AO;
#pragma unroll
    for (int it = 0; it < 8; ++it) dst[it * 512 + tid] = s8[it * 512 + tid];
  }
}

// =================== m97-style GEMM core (128x128 tile, BK=64) ===================
// A [M][KDIM] bf16 row-major, BT [N][KDIM] bf16 row-major (B transposed).
// LDS: Ab/Bb [128][64] bf16 (16KB each), single-buffered, staged via
// global_load_lds w16 with pre-swizzled global source (rule #21: linear dest +
// inverse-swizzled source + swizzled ds_read; involution u ^= row&7 on 16B units).
// 4 waves; wave tile 64x64 (4x4 frags of 16x16x32). 2 barriers per K-step.
template<int KDIM>
__device__ __forceinline__ void gemm_core(const u16* __restrict__ Ap,
                                          const u16* __restrict__ Bp,
                                          u16* Ab, u16* Bb,
                                          int wid, int lane, f32x4 acc[4][4]) {
  const int lane_lo = lane & 15, lane_hi = lane >> 4;
  const int wm = wid >> 1, wn = wid & 1;
  const int rl8 = lane >> 3, u8 = lane & 7;
  char* AbC = (char*)Ab;
  char* BbC = (char*)Bb;
  for (int k0 = 0; k0 < KDIM; k0 += 64) {
    // stage: each wave 4 A-insts + 4 B-insts, 8 rows per inst
#pragma unroll
    for (int i = 0; i < 4; ++i) {
      int row = wid * 32 + i * 8 + rl8;
      int usw = u8 ^ (row & 7);
      size_t goff = (size_t)row * KDIM + k0 + usw * 8;
      gload16(Ap + goff, AbC + wid * 4096 + i * 1024);
      gload16(Bp + goff, BbC + wid * 4096 + i * 1024);
    }
    __syncthreads();  // vmcnt(0) drain: staged data visible
#pragma unroll
    for (int ks = 0; ks < 2; ++ks) {
      bf16x8 av[4], bv[4];
#pragma unroll
      for (int mi = 0; mi < 4; ++mi) {
        int row = wm * 64 + mi * 16 + lane_lo;
        int usw = (ks * 4 + lane_hi) ^ (row & 7);
        av[mi] = *(const bf16x8*)(AbC + row * 128 + usw * 16);
      }
#pragma unroll
      for (int ni = 0; ni < 4; ++ni) {
        int row = wn * 64 + ni * 16 + lane_lo;
        int usw = (ks * 4 + lane_hi) ^ (row & 7);
        bv[ni] = *(const bf16x8*)(BbC + row * 128 + usw * 16);
      }
#pragma unroll
      for (int mi = 0; mi < 4; ++mi)
#pragma unroll
        for (int ni = 0; ni < 4; ++ni)
          acc[mi][ni] = __builtin_amdgcn_mfma_f32_16x16x32_bf16(av[mi], bv[ni], acc[mi][ni], 0, 0, 0);
    }
    __syncthreads();  // all reads done before next stage overwrites
  }
}

// FF1: H = gelu(X1 @ W1 + b1), K=512, N=2048 (16 n-blocks)
__global__ __launch_bounds__(256) void kff1(const u16* __restrict__ X1s,
                                            const u16* __restrict__ W1T,
                                            const float* __restrict__ b1v,
                                            u16* __restrict__ H) {
  __shared__ __align__(16) u16 Ab[8192];
  __shared__ __align__(16) u16 Bb[8192];
  int tid = threadIdx.x, lane = tid & 63, wid = tid >> 6;
  int nwg = gridDim.x, bid = blockIdx.x;
  int swz = (bid & 7) * (nwg >> 3) + (bid >> 3);  // XCD swizzle (nwg%8==0)
  int mb = swz >> 4, nb = swz & 15;
  const u16* Ap = X1s + (size_t)mb * 128 * 512;
  const u16* Bp = W1T + (size_t)nb * 128 * 512;
  f32x4 acc[4][4];
#pragma unroll
  for (int mi = 0; mi < 4; ++mi)
#pragma unroll
    for (int ni = 0; ni < 4; ++ni) acc[mi][ni] = (f32x4){0.f, 0.f, 0.f, 0.f};
  gemm_core<512>(Ap, Bp, Ab, Bb, wid, lane, acc);
  int lane_lo = lane & 15, lane_hi = lane >> 4;
  int wm = wid >> 1, wn = wid & 1;
#pragma unroll
  for (int mi = 0; mi < 4; ++mi)
#pragma unroll
    for (int j = 0; j < 4; ++j) {
      int rl = wm * 64 + mi * 16 + lane_hi * 4 + j;
      u16* hrow = H + ((size_t)mb * 128 + rl) * 2048 + (size_t)nb * 128;
#pragma unroll
      for (int ni = 0; ni < 4; ++ni) {
        int col = wn * 64 + ni * 16 + lane_lo;
        float u = acc[mi][ni][j] + b1v[nb * 128 + col];
        hrow[col] = f2bf(gelu_f(u));
      }
    }
}

// FF2: P = H @ W2 + b2 + X1 (pre-LN, f32), K=2048, N=512 (4 n-blocks)
__global__ __launch_bounds__(256) void kff2(const u16* __restrict__ H,
                                            const u16* __restrict__ W2T,
                                            const float* __restrict__ b2v,
                                            const u16* __restrict__ X1s,
                                            float* __restrict__ Ps) {
  __shared__ __align__(16) u16 Ab[8192];
  __shared__ __align__(16) u16 Bb[8192];
  int tid = threadIdx.x, lane = tid & 63, wid = tid >> 6;
  int nwg = gridDim.x, bid = blockIdx.x;
  int swz = (bid & 7) * (nwg >> 3) + (bid >> 3);
  int mb = swz >> 2, nb = swz & 3;
  const u16* Ap = H + (size_t)mb * 128 * 2048;
  const u16* Bp = W2T + (size_t)nb * 128 * 2048;
  f32x4 acc[4][4];
#pragma unroll
  for (int mi = 0; mi < 4; ++mi)
#pragma unroll
    for (int ni = 0; ni < 4; ++ni) acc[mi][ni] = (f32x4){0.f, 0.f, 0.f, 0.f};
  gemm_core<2048>(Ap, Bp, Ab, Bb, wid, lane, acc);
  int lane_lo = lane & 15, lane_hi = lane >> 4;
  int wm = wid >> 1, wn = wid & 1;
#pragma unroll
  for (int mi = 0; mi < 4; ++mi)
#pragma unroll
    for (int j = 0; j < 4; ++j) {
      int rl = wm * 64 + mi * 16 + lane_hi * 4 + j;
      size_t row = (size_t)mb * 128 + rl;
      const u16* xrow = X1s + row * 512 + nb * 128;
      float* prow = Ps + row * 512 + nb * 128;
#pragma unroll
      for (int ni = 0; ni < 4; ++ni) {
        int col = wn * 64 + ni * 16 + lane_lo;
        prow[col] = acc[mi][ni][j] + b2v[nb * 128 + col] + bf2f(xrow[col]);
      }
    }
}

// LN2 in-place over rows of P (= out): one wave per row
__global__ __launch_bounds__(512) void kln2(float* __restrict__ P,
                                            const float* __restrict__ g2,
                                            const float* __restrict__ bb2) {
  int wid = threadIdx.x >> 6, lane = threadIdx.x & 63;
  size_t row = (size_t)blockIdx.x * 8 + wid;
  float* pr = P + row * 512;
  float4 v0 = *(float4*)(pr + lane * 4);
  float4 v1 = *(float4*)(pr + 256 + lane * 4);
  float s = v0.x + v0.y + v0.z + v0.w + v1.x + v1.y + v1.z + v1.w;
  float q = v0.x * v0.x + v0.y * v0.y + v0.z * v0.z + v0.w * v0.w +
            v1.x * v1.x + v1.y * v1.y + v1.z * v1.z + v1.w * v1.w;
#pragma unroll
  for (int off = 1; off < 64; off <<= 1) { s += __shfl_xor(s, off); q += __shfl_xor(q, off); }
  float mu = s * (1.f / 512.f);
  float rs = rsqrtf(q * (1.f / 512.f) - mu * mu + 512.0f);
  float4 ga = *(const float4*)(g2 + lane * 4);
  float4 gb = *(const float4*)(g2 + 256 + lane * 4);
  float4 ba = *(const float4*)(bb2 + lane * 4);
  float4 bb = *(const float4*)(bb2 + 256 + lane * 4);
  v0.x = (v0.x - mu) * rs * ga.x + ba.x;
  v0.y = (v0.y - mu) * rs * ga.y + ba.y;
  v0.z = (v0.z - mu) * rs * ga.z + ba.z;
  v0.w = (v0.w - mu) * rs * ga.w + ba.w;
  v1.x = (v1.x - mu) * rs * gb.x + bb.x;
  v1.y = (v1.y - mu) * rs * gb.y + bb.y;
  v1.z = (v1.z - mu) * rs * gb.z + bb.z;
  v1.w = (v1.w - mu) * rs * gb.w + bb.w;
  *(float4*)(pr + lane * 4) = v0;
  *(float4*)(pr + 256 + lane * 4) = v1;
}

// ---------------- old fused MLP (fallback if ws too small for H) ----------------
__device__ __forceinline__ void iss_f1(bf16x8 dst[4], const u16* w1base, int ch, int p) {
#pragma unroll
  for (int k = 0; k < 4; ++k) {
    int ksl = k >> 1, ni = k & 1;
    dst[k] = *(const bf16x8*)(w1base + (size_t)(ch * 128 + ni * 16) * 512 + (p * 2 + ksl) * 32);
  }
}
__device__ __forceinline__ void iss_f2(bf16x8 dst[4], const u16* w2base, int ch, int h) {
#pragma unroll
  for (int k = 0; k < 4; ++k) {
    dst[k] = *(const bf16x8*)(w2base + (size_t)((h & 1) * 64 + k * 16) * 2048 + ch * 128 + (h >> 1) * 32);
  }
}

__global__ __launch_bounds__(512) void kmlp(const u16* __restrict__ X1,
                                            const u16* __restrict__ W1T,
                                            const u16* __restrict__ W2T,
                                            const float* __restrict__ b1v,
                                            const float* __restrict__ b2v,
                                            const float* __restrict__ g2,
                                            const float* __restrict__ bln2,
                                            float* __restrict__ out) {
  __shared__ u16 Abuf[32768];
  __shared__ u16 Hbuf[8192];
  char* Abase = (char*)Abuf;
  char* Hbase = (char*)Hbuf;
  float* rsum = (float*)Hbuf;
  float* rsq  = (float*)Hbuf + 256;
  float* mus  = (float*)Hbuf + 512;
  float* rss  = (float*)Hbuf + 576;
  int tid = threadIdx.x;
  int lane = tid & 63, wid = tid >> 6;
  int wm = wid >> 2, wnq = wid & 3;
  int lane_lo = lane & 15, lane_hi = lane >> 4;
  int m0 = blockIdx.x * 64;
  const u16* w1base = W1T + (size_t)(wnq * 32 + lane_lo) * 512 + lane_hi * 8;
  const u16* w2base = W2T + (size_t)(wnq * 128 + lane_lo) * 2048 + lane_hi * 8;
  {
    const bf16x8* src = (const bf16x8*)(X1 + (size_t)m0 * 512);
#pragma unroll
    for (int it = 0; it < 8; ++it) {
      int idx8 = it * 512 + tid;
      int row = idx8 >> 6;
      int byte = (idx8 * 16) ^ ((row & 7) << 4);
      *(bf16x8*)(Abase + byte) = src[idx8];
    }
  }
  __syncthreads();
  f32x4 accO[2][8];
#pragma unroll
  for (int mi = 0; mi < 2; ++mi)
#pragma unroll
    for (int ni = 0; ni < 8; ++ni) accO[mi][ni] = (f32x4){0.f, 0.f, 0.f, 0.f};
  bf16x8 bq[4][4];
  for (int ch = 0; ch < 16; ++ch) {
    f32x4 acc1[2][2];
#pragma unroll
    for (int mi = 0; mi < 2; ++mi)
#pragma unroll
      for (int ni = 0; ni < 2; ++ni) acc1[mi][ni] = (f32x4){0.f, 0.f, 0.f, 0.f};
    iss_f1(bq[0], w1base, ch, 0);
    iss_f1(bq[1], w1base, ch, 1);
    iss_f1(bq[2], w1base, ch, 2);
    iss_f1(bq[3], w1base, ch, 3);
#pragma unroll
    for (int p = 0; p < 8; ++p) {
#pragma unroll
      for (int ksl = 0; ksl < 2; ++ksl) {
        int ks = p * 2 + ksl;
        bf16x8 af[2];
#pragma unroll
        for (int mi = 0; mi < 2; ++mi) {
          int row = wm * 32 + mi * 16 + lane_lo;
          int byte = (row * 1024 + (ks * 32 + lane_hi * 8) * 2) ^ ((row & 7) << 4);
          af[mi] = *(const bf16x8*)(Abase + byte);
        }
#pragma unroll
        for (int ni = 0; ni < 2; ++ni)
#pragma unroll
          for (int mi = 0; mi < 2; ++mi)
            acc1[mi][ni] = __builtin_amdgcn_mfma_f32_16x16x32_bf16(af[mi], bq[p & 3][ksl * 2 + ni],
                                                                   acc1[mi][ni], 0, 0, 0);
      }
      if (p >= 4) iss_f2(bq[p & 3], w2base, ch, p - 4);
    }
#pragma unroll
    for (int mi = 0; mi < 2; ++mi)
#pragma unroll
      for (int ni = 0; ni < 2; ++ni)
#pragma unroll
        for (int j = 0; j < 4; ++j) {
          int rl = wm * 32 + mi * 16 + lane_hi * 4 + j;
          int col = wnq * 32 + ni * 16 + lane_lo;
          float u = acc1[mi][ni][j] + b1v[ch * 128 + col];
          float ge = gelu_f(u);
          int byte = (rl * 256 + col * 2) ^ ((rl & 7) << 4);
          *(u16*)(Hbase + byte) = f2bf(ge);
        }
    __syncthreads();
    bf16x8 ah[2];
#pragma unroll
    for (int h = 0; h < 8; ++h) {
      if ((h & 1) == 0) {
        int ks = h >> 1;
#pragma unroll
        for (int mi = 0; mi < 2; ++mi) {
          int row = wm * 32 + mi * 16 + lane_lo;
          int byte = (row * 256 + (ks * 32 + lane_hi * 8) * 2) ^ ((row & 7) << 4);
          ah[mi] = *(const bf16x8*)(Hbase + byte);
        }
      }
#pragma unroll
      for (int k = 0; k < 4; ++k) {
        int ni = (h & 1) * 4 + k;
#pragma unroll
        for (int mi = 0; mi < 2; ++mi)
          accO[mi][ni] = __builtin_amdgcn_mfma_f32_16x16x32_bf16(ah[mi], bq[h & 3][k],
                                                                 accO[mi][ni], 0, 0, 0);
      }
      if (h < 4) iss_f2(bq[h & 3], w2base, ch, h + 4);
    }
    __syncthreads();
  }
#pragma unroll
  for (int mi = 0; mi < 2; ++mi) {
#pragma unroll
    for (int j = 0; j < 4; ++j) {
      int rl = wm * 32 + mi * 16 + lane_hi * 4 + j;
      float s = 0.f, q = 0.f;
#pragma unroll
      for (int ni = 0; ni < 8; ++ni) {
        int col = wnq * 128 + ni * 16 + lane_lo;
        int abyte = (rl * 1024 + col * 2) ^ ((rl & 7) << 4);
        float x1v = bf2f(*(const u16*)(Abase + abyte));
        float val = accO[mi][ni][j] + b2v[col] + x1v;
        accO[mi][ni][j] = val;
        s += val; q += val * val;
      }
#pragma unroll
      for (int off = 1; off < 16; off <<= 1) { s += __shfl_xor(s, off); q += __shfl_xor(q, off); }
      if (lane_lo == 0) { rsum[rl * 4 + wnq] = s; rsq[rl * 4 + wnq] = q; }
    }
  }
  __syncthreads();
  if (tid < 64) {
    float s = rsum[tid * 4] + rsum[tid * 4 + 1] + rsum[tid * 4 + 2] + rsum[tid * 4 + 3];
    float q = rsq[tid * 4] + rsq[tid * 4 + 1] + rsq[tid * 4 + 2] + rsq[tid * 4 + 3];
    float mu = s * (1.f / 512.f);
    float var = q * (1.f / 512.f) - mu * mu;
    mus[tid] = mu;
    rss[tid] = rsqrtf(var + 512.0f);
  }
  __syncthreads();
#pragma unroll
  for (int mi = 0; mi < 2; ++mi) {
#pragma unroll
    for (int j = 0; j < 4; ++j) {
      int rl = wm * 32 + mi * 16 + lane_hi * 4 + j;
      float mu = mus[rl], rs = rss[rl];
      float* orow = out + (size_t)(m0 + rl) * 512;
#pragma unroll
      for (int ni = 0; ni < 8; ++ni) {
        int col = wnq * 128 + ni * 16 + lane_lo;
        orow[col] = (accO[mi][ni][j] - mu) * rs * g2[col] + bln2[col];
      }
    }
  }
}

extern "C" void kernel_launch(void* const* d_in, const int* in_sizes, int n_in,
                              void* d_out, int out_size, void* d_ws, size_t ws_size,
                              hipStream_t stream) {
  const float* x   = (const float*)d_in[0];
  const float* Wq  = (const float*)d_in[1];
  const float* Wk  = (const float*)d_in[2];
  const float* Wv  = (const float*)d_in[3];
  const float* Wp  = (const float*)d_in[4];
  const float* bp  = (const float*)d_in[5];
  const float* W1  = (const float*)d_in[6];
  const float* b1  = (const float*)d_in[7];
  const float* W2  = (const float*)d_in[8];
  const float* b2  = (const float*)d_in[9];
  const float* g1  = (const float*)d_in[10];
  const float* bb1 = (const float*)d_in[11];
  const float* g2  = (const float*)d_in[12];
  const float* bb2 = (const float*)d_in[13];
  float* out = (float*)d_out;

  char* ws = (char*)d_ws;
  float* G  = (float*)ws;                    // 64KB region (256KB reserved)
  u16* WvpT = (u16*)(ws + (256 << 10));      // 128KB
  u16* W1T  = (u16*)(ws + (1 << 20));        // 2MB
  u16* W2T  = (u16*)(ws + (3 << 20));        // 2MB
  u16* Z    = (u16*)(ws + (5 << 20));        // 16MB
  u16* X1   = (u16*)(ws + (21 << 20));       // 64MB
  u16* H    = (u16*)(ws + (85ull << 20));    // up to 256MB (M-sliced if tight)

  hipLaunchKernelGGL(kprep_G,   dim3(64),   dim3(256), 0, stream, Wq, Wk, G);
  hipLaunchKernelGGL(kprep_Wvp, dim3(256),  dim3(256), 0, stream, Wv, Wp, WvpT);
  hipLaunchKernelGGL(kprep_W1T, dim3(4096), dim3(256), 0, stream, W1, W1T);
  hipLaunchKernelGGL(kprep_W2T, dim3(4096), dim3(256), 0, stream, W2, W2T);
  hipLaunchKernelGGL(ktoken,    dim3(4096), dim3(256), 0, stream, x, G, Z);
  hipLaunchKernelGGL(kattn,     dim3(1024), dim3(512), 0, stream, Z, WvpT, bp, x, g1, bb1, X1);

  // pick smallest slice count whose H fits in ws
  const size_t hbase = 85ull << 20;
  int S = 0;
  for (int c = 1; c <= 16; c <<= 1) {
    if (hbase + (268435456ull / (size_t)c) <= ws_size) { S = c; break; }
  }
  if (S) {
    int Ms = MROWS / S;  // rows per slice (>= 4096, multiple of 128)
    for (int s = 0; s < S; ++s) {
      const u16* x1s = X1 + (size_t)s * Ms * 512;
      float* outs = out + (size_t)s * Ms * 512;
      hipLaunchKernelGGL(kff1, dim3((Ms / 128) * 16), dim3(256), 0, stream, x1s, W1T, b1, H);
      hipLaunchKernelGGL(kff2, dim3((Ms / 128) * 4),  dim3(256), 0, stream, H, W2T, b2, x1s, outs);
    }
    hipLaunchKernelGGL(kln2, dim3(8192), dim3(512), 0, stream, out, g2, bb2);
  } else {
    hipLaunchKernelGGL(kmlp, dim3(1024), dim3(512), 0, stream, X1, W1T, W2T, b1, b2, g2, bb2, out);
  }
}

// Round 7
// 720.289 us; speedup vs baseline: 1.7522x; 1.1174x over previous
//
#include <hip/hip_runtime.h>
#include <hip/hip_bf16.h>
#include <math.h>

typedef __bf16 bf16x8 __attribute__((ext_vector_type(8)));
typedef float f32x4 __attribute__((ext_vector_type(4)));
typedef unsigned short u16;
typedef unsigned int u32;
typedef u16 u16x4 __attribute__((ext_vector_type(4)));

#define TOKENS 16384
#define MROWS  65536

__device__ __forceinline__ u16 f2bf(float f) {
  union { __hip_bfloat16 h; u16 u; } c;
  c.h = __float2bfloat16(f);
  return c.u;
}
__device__ __forceinline__ float bf2f(u16 u) {
  union { u16 u; __hip_bfloat16 h; } c;
  c.u = u;
  return __bfloat162float(c.h);
}
// sigmoid-form gelu: u * sigma(2y), algebraically == tanh-form (validated r5/r6)
__device__ __forceinline__ float gelu_f(float u) {
  float y2 = u * fmaf(0.07135481283f, u * u, 1.595769122f);  // 2*0.79788456*(u+0.044715u^3)
  float e = __expf(-y2);
  return u / (1.f + e);
}
// async global->LDS, 16B per lane; LDS dest is wave-uniform base + lane*16
__device__ __forceinline__ void gload16(const void* g, void* l) {
  __builtin_amdgcn_global_load_lds(
      (const __attribute__((address_space(1))) void*)g,
      (__attribute__((address_space(3))) void*)l, 16, 0, 0);
}

// ---------------- prep kernels ----------------
__global__ void kprep_G(const float* __restrict__ Wq, const float* __restrict__ Wk,
                        float* __restrict__ G) {
  int id = blockIdx.x * 256 + threadIdx.x;  // 16384
  int c = id >> 7, c2 = id & 127;
  const float4* a = (const float4*)(Wq + (size_t)c * 512);
  const float4* b = (const float4*)(Wk + (size_t)c2 * 512);
  float s = 0.f;
#pragma unroll 8
  for (int i = 0; i < 128; ++i) {
    float4 xa = a[i], yb = b[i];
    s += xa.x * yb.x + xa.y * yb.y + xa.z * yb.z + xa.w * yb.w;
  }
  G[id] = s * 0.044194173824159216f;
}

__global__ void kprep_Wvp(const float* __restrict__ Wv, const float* __restrict__ Wp,
                          u16* __restrict__ WvpT) {
  int id = blockIdx.x * 256 + threadIdx.x;  // 65536 : e*128+c
  int e = id >> 7, c = id & 127;
  float s = 0.f;
#pragma unroll 4
  for (int d = 0; d < 512; ++d) s += Wv[(size_t)c * 512 + d] * Wp[(size_t)d * 512 + e];
  WvpT[id] = f2bf(s);
}

__global__ void kprep_W1T(const float* __restrict__ W1, u16* __restrict__ W1T) {
  int id = blockIdx.x * 256 + threadIdx.x;  // 1M : f*512+e
  int f = id >> 9, e = id & 511;
  W1T[id] = f2bf(W1[(size_t)e * 2048 + f]);
}
// W2T with the H column permutation applied per 128-block:
// stored slot fs holds true f_inner = (fs>>6)*64 + (fs&3)*16 + ((fs>>2)&15)
// (must match kff1's H store layout; dot over permuted k is invariant)
__global__ void kprep_W2T(const float* __restrict__ W2, u16* __restrict__ W2T) {
  int id = blockIdx.x * 256 + threadIdx.x;  // 1M : e*2048 + f_stored
  int e = id >> 11, fst = id & 2047;
  int fb = fst >> 7, fs = fst & 127;
  int f_true = fb * 128 + ((fs >> 6) << 6) + ((fs & 3) << 4) + ((fs >> 2) & 15);
  W2T[id] = f2bf(W2[(size_t)f_true * 512 + e]);
}

// ---------------- token attention: Z = softmax(mask(S G S^T)) S ----------------
__global__ __launch_bounds__(256) void ktoken(const float* __restrict__ x,
                                              const float* __restrict__ G,
                                              u16* __restrict__ Z) {
  __shared__ float Ss[4 * 512];
  __shared__ float T1s[4 * 512];
  __shared__ float Ws[4 * 16];
  int tid = threadIdx.x;
  int wave = tid >> 6, lane = tid & 63;
  int tok0 = blockIdx.x * 4;
  {
    const float4* xsrc = (const float4*)(x + (size_t)tok0 * 512);
    float4* sdst = (float4*)Ss;
    sdst[tid] = xsrc[tid];
    sdst[256 + tid] = xsrc[256 + tid];
  }
  __syncthreads();
  {
    const float* Sw = Ss + wave * 512;
    float a00 = 0, a01 = 0, a10 = 0, a11 = 0, a20 = 0, a21 = 0, a30 = 0, a31 = 0;
#pragma unroll 4
    for (int c = 0; c < 128; ++c) {
      float2 gg = ((const float2*)(G + (size_t)c * 128))[lane];
      float s0 = Sw[c], s1 = Sw[128 + c], s2 = Sw[256 + c], s3 = Sw[384 + c];
      a00 += s0 * gg.x; a01 += s0 * gg.y;
      a10 += s1 * gg.x; a11 += s1 * gg.y;
      a20 += s2 * gg.x; a21 += s2 * gg.y;
      a30 += s3 * gg.x; a31 += s3 * gg.y;
    }
    float* Tw = T1s + wave * 512;
    int c2 = lane * 2;
    Tw[c2] = a00; Tw[c2 + 1] = a01;
    Tw[128 + c2] = a10; Tw[128 + c2 + 1] = a11;
    Tw[256 + c2] = a20; Tw[256 + c2 + 1] = a21;
    Tw[384 + c2] = a30; Tw[384 + c2 + 1] = a31;
  }
  __syncthreads();
  if (lane < 16) {
    int i = lane >> 2, j = lane & 3;
    const float* Tw = T1s + wave * 512 + i * 128;
    const float* Sw = Ss + wave * 512 + j * 128;
    float d = 0.f;
#pragma unroll 8
    for (int c = 0; c < 128; ++c) d += Tw[c] * Sw[c];
    Ws[wave * 16 + i * 4 + j] = d;
  }
  __syncthreads();
  {
    float p[4][4];
    const float* ww = Ws + wave * 16;
#pragma unroll
    for (int i = 0; i < 4; ++i) {
      float m = -1e30f;
      for (int j = 0; j <= i; ++j) m = fmaxf(m, ww[i * 4 + j]);
      float s = 0.f;
      for (int j = 0; j <= i; ++j) { p[i][j] = __expf(ww[i * 4 + j] - m); s += p[i][j]; }
      float inv = 1.f / s;
      for (int j = 0; j <= i; ++j) p[i][j] *= inv;
      for (int j = i + 1; j < 4; ++j) p[i][j] = 0.f;
    }
    const float* Sw = Ss + wave * 512;
    int c = lane * 2;
    u32* zout = (u32*)(Z + (size_t)(tok0 + wave) * 512);
#pragma unroll
    for (int i = 0; i < 4; ++i) {
      float z0 = 0.f, z1 = 0.f;
#pragma unroll
      for (int j = 0; j < 4; ++j) {
        z0 += p[i][j] * Sw[j * 128 + c];
        z1 += p[i][j] * Sw[j * 128 + c + 1];
      }
      zout[i * 64 + lane] = (u32)f2bf(z0) | ((u32)f2bf(z1) << 16);
    }
  }
}

// ---------------- attn-out projection + bias + residual + LN1 -> X1 (bf16) ----------------
__global__ __launch_bounds__(512) void kattn(const u16* __restrict__ Z,
                                             const u16* __restrict__ WvpT,
                                             const float* __restrict__ bp,
                                             const float* __restrict__ x,
                                             const float* __restrict__ g1,
                                             const float* __restrict__ bln1,
                                             u16* __restrict__ X1) {
  __shared__ u16 AO[32768];
  __shared__ float rsum[64 * 4];
  __shared__ float rsq[64 * 4];
  __shared__ float mus[64];
  __shared__ float rss[64];
  char* smem = (char*)AO;
  int tid = threadIdx.x;
  int lane = tid & 63, wid = tid >> 6;
  int wm = wid >> 2, wnq = wid & 3;
  int lane_lo = lane & 15, lane_hi = lane >> 4;
  int m0 = blockIdx.x * 64;
  {
    const bf16x8* src = (const bf16x8*)(Z + (size_t)m0 * 128);
#pragma unroll
    for (int it = 0; it < 2; ++it) {
      int idx8 = it * 512 + tid;
      int row = idx8 >> 4;
      int byte = (idx8 * 16) ^ ((row & 7) << 4);
      *(bf16x8*)(smem + byte) = src[idx8];
    }
  }
  __syncthreads();
  f32x4 acc[2][8];
#pragma unroll
  for (int mi = 0; mi < 2; ++mi)
#pragma unroll
    for (int ni = 0; ni < 8; ++ni) acc[mi][ni] = (f32x4){0.f, 0.f, 0.f, 0.f};
#pragma unroll
  for (int ks = 0; ks < 4; ++ks) {
    bf16x8 af[2];
#pragma unroll
    for (int mi = 0; mi < 2; ++mi) {
      int row = wm * 32 + mi * 16 + lane_lo;
      int byte = (row * 256 + (ks * 32 + lane_hi * 8) * 2) ^ ((row & 7) << 4);
      af[mi] = *(const bf16x8*)(smem + byte);
    }
#pragma unroll
    for (int ni = 0; ni < 8; ++ni) {
      int n = wnq * 128 + ni * 16 + lane_lo;
      bf16x8 bfr = *(const bf16x8*)(WvpT + (size_t)n * 128 + ks * 32 + lane_hi * 8);
#pragma unroll
      for (int mi = 0; mi < 2; ++mi)
        acc[mi][ni] = __builtin_amdgcn_mfma_f32_16x16x32_bf16(af[mi], bfr, acc[mi][ni], 0, 0, 0);
    }
  }
#pragma unroll
  for (int mi = 0; mi < 2; ++mi) {
#pragma unroll
    for (int j = 0; j < 4; ++j) {
      int rl = wm * 32 + mi * 16 + lane_hi * 4 + j;
      int R = m0 + rl;
      const float* xrow = x + (size_t)(R >> 2) * 512;
      float s = 0.f, q = 0.f;
#pragma unroll
      for (int ni = 0; ni < 8; ++ni) {
        int col = wnq * 128 + ni * 16 + lane_lo;
        float val = acc[mi][ni][j] + bp[col] + xrow[col];
        acc[mi][ni][j] = val;
        s += val; q += val * val;
      }
#pragma unroll
      for (int off = 1; off < 16; off <<= 1) { s += __shfl_xor(s, off); q += __shfl_xor(q, off); }
      if (lane_lo == 0) { rsum[rl * 4 + wnq] = s; rsq[rl * 4 + wnq] = q; }
    }
  }
  __syncthreads();
  if (tid < 64) {
    float s = rsum[tid * 4] + rsum[tid * 4 + 1] + rsum[tid * 4 + 2] + rsum[tid * 4 + 3];
    float q = rsq[tid * 4] + rsq[tid * 4 + 1] + rsq[tid * 4 + 2] + rsq[tid * 4 + 3];
    float mu = s * (1.f / 512.f);
    float var = q * (1.f / 512.f) - mu * mu;
    mus[tid] = mu;
    rss[tid] = rsqrtf(var + 512.0f);
  }
  __syncthreads();
#pragma unroll
  for (int mi = 0; mi < 2; ++mi) {
#pragma unroll
    for (int j = 0; j < 4; ++j) {
      int rl = wm * 32 + mi * 16 + lane_hi * 4 + j;
      float mu = mus[rl], rs = rss[rl];
#pragma unroll
      for (int ni = 0; ni < 8; ++ni) {
        int col = wnq * 128 + ni * 16 + lane_lo;
        AO[rl * 512 + col] = f2bf((acc[mi][ni][j] - mu) * rs * g1[col] + bln1[col]);
      }
    }
  }
  __syncthreads();
  {
    bf16x8* dst = (bf16x8*)(X1 + (size_t)m0 * 512);
    const bf16x8* s8 = (const bf16x8*)AO;
#pragma unroll
    for (int it = 0; it < 8; ++it) dst[it * 512 + tid] = s8[it * 512 + tid];
  }
}

// =================== m97-style GEMM core (128x128 tile, BK=64) ===================
template<int KDIM>
__device__ __forceinline__ void gemm_core(const u16* __restrict__ Ap,
                                          const u16* __restrict__ Bp,
                                          u16* Ab, u16* Bb,
                                          int wid, int lane, f32x4 acc[4][4]) {
  const int lane_lo = lane & 15, lane_hi = lane >> 4;
  const int wm = wid >> 1, wn = wid & 1;
  const int rl8 = lane >> 3, u8 = lane & 7;
  char* AbC = (char*)Ab;
  char* BbC = (char*)Bb;
  for (int k0 = 0; k0 < KDIM; k0 += 64) {
    // stage: each wave 4 A-insts + 4 B-insts, 8 rows per inst
#pragma unroll
    for (int i = 0; i < 4; ++i) {
      int row = wid * 32 + i * 8 + rl8;
      int usw = u8 ^ (row & 7);
      size_t goff = (size_t)row * KDIM + k0 + usw * 8;
      gload16(Ap + goff, AbC + wid * 4096 + i * 1024);
      gload16(Bp + goff, BbC + wid * 4096 + i * 1024);
    }
    __syncthreads();  // staged data visible
#pragma unroll
    for (int ks = 0; ks < 2; ++ks) {
      bf16x8 av[4], bv[4];
#pragma unroll
      for (int mi = 0; mi < 4; ++mi) {
        int row = wm * 64 + mi * 16 + lane_lo;
        int usw = (ks * 4 + lane_hi) ^ (row & 7);
        av[mi] = *(const bf16x8*)(AbC + row * 128 + usw * 16);
      }
#pragma unroll
      for (int ni = 0; ni < 4; ++ni) {
        int row = wn * 64 + ni * 16 + lane_lo;
        int usw = (ks * 4 + lane_hi) ^ (row & 7);
        bv[ni] = *(const bf16x8*)(BbC + row * 128 + usw * 16);
      }
#pragma unroll
      for (int mi = 0; mi < 4; ++mi)
#pragma unroll
        for (int ni = 0; ni < 4; ++ni)
          acc[mi][ni] = __builtin_amdgcn_mfma_f32_16x16x32_bf16(av[mi], bv[ni], acc[mi][ni], 0, 0, 0);
    }
    __syncthreads();  // all reads done before next stage overwrites
  }
}

// FF1: H = gelu(X1 @ W1 + b1), K=512, N=2048 (16 n-blocks)
// H stored with per-128-block column permutation (see kprep_W2T) -> 8B packed stores.
// XCD co-location: all 16 nb of one mb run consecutively on one XCD (bid%8 = XCD).
__global__ __launch_bounds__(256) void kff1(const u16* __restrict__ X1s,
                                            const u16* __restrict__ W1T,
                                            const float* __restrict__ b1v,
                                            u16* __restrict__ H) {
  __shared__ __align__(16) u16 Ab[8192];
  __shared__ __align__(16) u16 Bb[8192];
  int tid = threadIdx.x, lane = tid & 63, wid = tid >> 6;
  int nwg = gridDim.x, bid = blockIdx.x;
  int m128 = nwg >> 4;
  int xcd = bid & 7, idx = bid >> 3;
  int mb = xcd * (m128 >> 3) + (idx >> 4);
  int nb = idx & 15;
  const u16* Ap = X1s + (size_t)mb * 128 * 512;
  const u16* Bp = W1T + (size_t)nb * 128 * 512;
  f32x4 acc[4][4];
#pragma unroll
  for (int mi = 0; mi < 4; ++mi)
#pragma unroll
    for (int ni = 0; ni < 4; ++ni) acc[mi][ni] = (f32x4){0.f, 0.f, 0.f, 0.f};
  gemm_core<512>(Ap, Bp, Ab, Bb, wid, lane, acc);
  int lane_lo = lane & 15, lane_hi = lane >> 4;
  int wm = wid >> 1, wn = wid & 1;
  float bvals[4];
#pragma unroll
  for (int ni = 0; ni < 4; ++ni) bvals[ni] = b1v[nb * 128 + wn * 64 + ni * 16 + lane_lo];
  int colb = nb * 128 + (wn * 16 + lane_lo) * 4;  // stored position of this lane's 4 values
#pragma unroll
  for (int mi = 0; mi < 4; ++mi)
#pragma unroll
    for (int j = 0; j < 4; ++j) {
      int rl = wm * 64 + mi * 16 + lane_hi * 4 + j;
      u16x4 pk;
#pragma unroll
      for (int ni = 0; ni < 4; ++ni)
        pk[ni] = f2bf(gelu_f(acc[mi][ni][j] + bvals[ni]));
      *(u16x4*)(H + ((size_t)mb * 128 + rl) * 2048 + colb) = pk;
    }
}

// FF2: P = H @ W2 + b2 + X1 (pre-LN, f32), K=2048, N=512 (4 n-blocks)
// XCD co-location: 4 nb of one mb consecutive on one XCD -> H stripe (512KB) L2-hits.
__global__ __launch_bounds__(256) void kff2(const u16* __restrict__ H,
                                            const u16* __restrict__ W2T,
                                            const float* __restrict__ b2v,
                                            const u16* __restrict__ X1s,
                                            float* __restrict__ Ps) {
  __shared__ __align__(16) u16 Ab[8192];
  __shared__ __align__(16) u16 Bb[8192];
  int tid = threadIdx.x, lane = tid & 63, wid = tid >> 6;
  int nwg = gridDim.x, bid = blockIdx.x;
  int m128 = nwg >> 2;
  int xcd = bid & 7, idx = bid >> 3;
  int mb = xcd * (m128 >> 3) + (idx >> 2);
  int nb = idx & 3;
  const u16* Ap = H + (size_t)mb * 128 * 2048;
  const u16* Bp = W2T + (size_t)nb * 128 * 2048;
  f32x4 acc[4][4];
#pragma unroll
  for (int mi = 0; mi < 4; ++mi)
#pragma unroll
    for (int ni = 0; ni < 4; ++ni) acc[mi][ni] = (f32x4){0.f, 0.f, 0.f, 0.f};
  gemm_core<2048>(Ap, Bp, Ab, Bb, wid, lane, acc);
  int lane_lo = lane & 15, lane_hi = lane >> 4;
  int wm = wid >> 1, wn = wid & 1;
#pragma unroll
  for (int mi = 0; mi < 4; ++mi)
#pragma unroll
    for (int j = 0; j < 4; ++j) {
      int rl = wm * 64 + mi * 16 + lane_hi * 4 + j;
      size_t row = (size_t)mb * 128 + rl;
      const u16* xrow = X1s + row * 512 + nb * 128;
      float* prow = Ps + row * 512 + nb * 128;
#pragma unroll
      for (int ni = 0; ni < 4; ++ni) {
        int col = wn * 64 + ni * 16 + lane_lo;
        prow[col] = acc[mi][ni][j] + b2v[nb * 128 + col] + bf2f(xrow[col]);
      }
    }
}

// LN2 in-place over rows of P (= out): one wave per row
__global__ __launch_bounds__(512) void kln2(float* __restrict__ P,
                                            const float* __restrict__ g2,
                                            const float* __restrict__ bb2) {
  int wid = threadIdx.x >> 6, lane = threadIdx.x & 63;
  size_t row = (size_t)blockIdx.x * 8 + wid;
  float* pr = P + row * 512;
  float4 v0 = *(float4*)(pr + lane * 4);
  float4 v1 = *(float4*)(pr + 256 + lane * 4);
  float s = v0.x + v0.y + v0.z + v0.w + v1.x + v1.y + v1.z + v1.w;
  float q = v0.x * v0.x + v0.y * v0.y + v0.z * v0.z + v0.w * v0.w +
            v1.x * v1.x + v1.y * v1.y + v1.z * v1.z + v1.w * v1.w;
#pragma unroll
  for (int off = 1; off < 64; off <<= 1) { s += __shfl_xor(s, off); q += __shfl_xor(q, off); }
  float mu = s * (1.f / 512.f);
  float rs = rsqrtf(q * (1.f / 512.f) - mu * mu + 512.0f);
  float4 ga = *(const float4*)(g2 + lane * 4);
  float4 gb = *(const float4*)(g2 + 256 + lane * 4);
  float4 ba = *(const float4*)(bb2 + lane * 4);
  float4 bb = *(const float4*)(bb2 + 256 + lane * 4);
  v0.x = (v0.x - mu) * rs * ga.x + ba.x;
  v0.y = (v0.y - mu) * rs * ga.y + ba.y;
  v0.z = (v0.z - mu) * rs * ga.z + ba.z;
  v0.w = (v0.w - mu) * rs * ga.w + ba.w;
  v1.x = (v1.x - mu) * rs * gb.x + bb.x;
  v1.y = (v1.y - mu) * rs * gb.y + bb.y;
  v1.z = (v1.z - mu) * rs * gb.z + bb.z;
  v1.w = (v1.w - mu) * rs * gb.w + bb.w;
  *(float4*)(pr + lane * 4) = v0;
  *(float4*)(pr + 256 + lane * 4) = v1;
}

extern "C" void kernel_launch(void* const* d_in, const int* in_sizes, int n_in,
                              void* d_out, int out_size, void* d_ws, size_t ws_size,
                              hipStream_t stream) {
  const float* x   = (const float*)d_in[0];
  const float* Wq  = (const float*)d_in[1];
  const float* Wk  = (const float*)d_in[2];
  const float* Wv  = (const float*)d_in[3];
  const float* Wp  = (const float*)d_in[4];
  const float* bp  = (const float*)d_in[5];
  const float* W1  = (const float*)d_in[6];
  const float* b1  = (const float*)d_in[7];
  const float* W2  = (const float*)d_in[8];
  const float* b2  = (const float*)d_in[9];
  const float* g1  = (const float*)d_in[10];
  const float* bb1 = (const float*)d_in[11];
  const float* g2  = (const float*)d_in[12];
  const float* bb2 = (const float*)d_in[13];
  float* out = (float*)d_out;

  char* ws = (char*)d_ws;
  float* G  = (float*)ws;                    // 64KB region (256KB reserved)
  u16* WvpT = (u16*)(ws + (256 << 10));      // 128KB
  u16* W1T  = (u16*)(ws + (1 << 20));        // 2MB
  u16* W2T  = (u16*)(ws + (3 << 20));        // 2MB
  u16* Z    = (u16*)(ws + (5 << 20));        // 16MB
  u16* X1   = (u16*)(ws + (21 << 20));       // 64MB
  u16* H    = (u16*)(ws + (85ull << 20));    // up to 256MB (M-sliced if tight)

  hipLaunchKernelGGL(kprep_G,   dim3(64),   dim3(256), 0, stream, Wq, Wk, G);
  hipLaunchKernelGGL(kprep_Wvp, dim3(256),  dim3(256), 0, stream, Wv, Wp, WvpT);
  hipLaunchKernelGGL(kprep_W1T, dim3(4096), dim3(256), 0, stream, W1, W1T);
  hipLaunchKernelGGL(kprep_W2T, dim3(4096), dim3(256), 0, stream, W2, W2T);
  hipLaunchKernelGGL(ktoken,    dim3(4096), dim3(256), 0, stream, x, G, Z);
  hipLaunchKernelGGL(kattn,     dim3(1024), dim3(512), 0, stream, Z, WvpT, bp, x, g1, bb1, X1);

  // pick smallest slice count whose H fits in ws
  const size_t hbase = 85ull << 20;
  int S = 64;
  for (int c = 1; c <= 64; c <<= 1) {
    if (hbase + (268435456ull / (size_t)c) <= ws_size) { S = c; break; }
  }
  int Ms = MROWS / S;  // rows per slice (multiple of 1024; Ms/128 divisible by 8)
  for (int s = 0; s < S; ++s) {
    const u16* x1s = X1 + (size_t)s * Ms * 512;
    float* outs = out + (size_t)s * Ms * 512;
    hipLaunchKernelGGL(kff1, dim3((Ms / 128) * 16), dim3(256), 0, stream, x1s, W1T, b1, H);
    hipLaunchKernelGGL(kff2, dim3((Ms / 128) * 4),  dim3(256), 0, stream, H, W2T, b2, x1s, outs);
  }
  hipLaunchKernelGGL(kln2, dim3(8192), dim3(512), 0, stream, out, g2, bb2);
}